// Round 12
// baseline (166.643 us; speedup 1.0000x reference)
//
#include <hip/hip_runtime.h>

// Problem constants
#define HDIM 64
#define LSEQ 2048
#define BATCH 16
#define LN_EPS 1e-5f
#define D_EPS 1e-6f
#define NSEG 16      // segments per batch
#define CPS 8        // chunks per segment (16 tokens each) -> 128 tokens/block

typedef unsigned short u16;
typedef unsigned int   u32;

__device__ __forceinline__ float bf2f(u16 v) {
    return __uint_as_float(((u32)v) << 16);
}
__device__ __forceinline__ u16 f2bf(float f) {   // round-to-nearest-even
    u32 u = __float_as_uint(f);
    return (u16)((u + 0x7FFFu + ((u >> 16) & 1u)) >> 16);
}

// ---------------- shared-memory overlay (bytes) ----------------
// Phase A scratch (dead after preprocess):
#define P_SW1   0        // f32[64*132]  33792
#define P_SW2   33792    // f32[128*68]  34816
#define P_ET    68608    // f32[64*68]   17408
#define P_HIDT  86016    // f32[128*68]  34816
#define P_RED1  120832   // f32[4*66]    1056
#define P_RED2  121888   // f32[4*66]    1056
#define P_SMU   122944   // f32[68]      272
#define P_SRSTD 123216   // f32[68]      272
// Persistent across phases A/B:
#define H_ROWS  123488   // f32[128*68]  34816  (bf16-rounded h, row-major)
#define H_INVD  158304   // f32[128]     512
#define SMEM_BYTES 158816
// Compose overlays phase-A scratch:
#define C_S     0        // f32[64*68]   17408
#define C_V     17408    // f32[64*68]   17408
#define C_BM    34816    // f32[16*68]   4352
#define C_Z     39168    // f32[16*68]   4352
#define C_GM    43520    // f32[16*17]   1088
#define C_IVD   44608    // f32[16]      64
// Final phase (finisher blocks only; everything is dead by then):
#define F_PSUM  0        // f32[4*72]    1152
#define F_RL    1152     // f32[64]      256
#define F_CS    1408     // f32[64]      256
#define F_RS    1664     // f32[64]      256

// ---------------------------------------------------------------------------
// Single kernel: fused preprocess + compose + (blocks 0..15) final.
// 256 blocks x 256 threads, block = (batch b, segment s); all co-resident
// (grid == CU count, 1 block/CU at 159 KB LDS). After PK writeback every
// block does release-fence + atomicAdd(counter); blocks 0..15 spin for
// count==256 (acquire) and then run the serial segment pass + projection
// for batch = blockIdx. Math is bit-identical to round 11.
// ---------------------------------------------------------------------------
__global__ __launch_bounds__(256, 1) void fused_kernel(
    const int* __restrict__ seq, const float* __restrict__ embed,
    const float* __restrict__ W1, const float* __restrict__ b1,
    const float* __restrict__ W2, const float* __restrict__ b2,
    const float* __restrict__ gamma, const float* __restrict__ beta,
    const float* __restrict__ Wr, const float* __restrict__ br,
    const float* __restrict__ Wo, const float* __restrict__ bo,
    u32* __restrict__ PK, u16* __restrict__ q_ws,
    u32* __restrict__ counter, float* __restrict__ out)
{
    __shared__ __align__(16) char smem[SMEM_BYTES];
    const int t = threadIdx.x;
    const int b = blockIdx.x >> 4;
    const int s = blockIdx.x & 15;
    const int tok0 = 1920 - 128 * s;          // first token of this block

    float* hrows  = (float*)(smem + H_ROWS);
    float* invd_l = (float*)(smem + H_INVD);

    // ======================= Phase A: preprocess ==========================
    {
        float* sW1   = (float*)(smem + P_SW1);
        float* sW2   = (float*)(smem + P_SW2);
        float* eT    = (float*)(smem + P_ET);
        float* hidT  = (float*)(smem + P_HIDT);
        float* red1  = (float*)(smem + P_RED1);
        float* red2  = (float*)(smem + P_RED2);
        float* smu   = (float*)(smem + P_SMU);
        float* srstd = (float*)(smem + P_SRSTD);

        // stage W1 (64x128, stride 132) and W2 (128x64, stride 68) once
        {
            const float4* s1 = (const float4*)W1;   // 2048 float4
#pragma unroll
            for (int q = 0; q < 8; ++q) {
                const int m = t + 256 * q;
                const int row = m >> 5, col = m & 31;
                *(float4*)&sW1[row * 132 + col * 4] = s1[m];
            }
            const float4* s2 = (const float4*)W2;   // 2048 float4
#pragma unroll
            for (int q = 0; q < 8; ++q) {
                const int m = t + 256 * q;
                const int row = m >> 4, col = m & 15;
                *(float4*)&sW2[row * 68 + col * 4] = s2[m];
            }
        }

        for (int it = 0; it < 2; ++it) {
            const int g0 = b * LSEQ + tok0 + 64 * it;   // global token base
            __syncthreads();   // W staging (it=0) / prior tile reads (it=1)

            // stage embeddings transposed: thread (tk = t>>2, p = t&3)
            {
                const int tk = t >> 2, p = t & 3;
                const int v = seq[g0 + tk];
                const float* er = embed + v * HDIM + 16 * p;
#pragma unroll
                for (int q = 0; q < 4; ++q) {
                    const float4 ev = *(const float4*)(er + 4 * q);
                    const int d = 16 * p + 4 * q;
                    eT[(d + 0) * 68 + tk] = ev.x;
                    eT[(d + 1) * 68 + tk] = ev.y;
                    eT[(d + 2) * 68 + tk] = ev.z;
                    eT[(d + 3) * 68 + tk] = ev.w;
                }
            }
            __syncthreads();

            const int r = t >> 4;   // token quad
            const int c = t & 15;   // out quad

            // MLP1: hid = relu(e W1 + b1)
            {
                float acc0[4][4], acc1[4][4];
#pragma unroll
                for (int o = 0; o < 4; ++o) {
                    const float bA = b1[4 * c + o];
                    const float bB = b1[64 + 4 * c + o];
#pragma unroll
                    for (int j = 0; j < 4; ++j) { acc0[j][o] = bA; acc1[j][o] = bB; }
                }
                for (int k = 0; k < 64; ++k) {
                    const float4 ev = *(const float4*)&eT[k * 68 + 4 * r];
                    const float4 wa = *(const float4*)&sW1[k * 132 + 4 * c];
                    const float4 wb = *(const float4*)&sW1[k * 132 + 64 + 4 * c];
                    const float e4[4] = {ev.x, ev.y, ev.z, ev.w};
                    const float a4[4] = {wa.x, wa.y, wa.z, wa.w};
                    const float b4[4] = {wb.x, wb.y, wb.z, wb.w};
#pragma unroll
                    for (int j = 0; j < 4; ++j)
#pragma unroll
                        for (int o = 0; o < 4; ++o) {
                            acc0[j][o] = fmaf(e4[j], a4[o], acc0[j][o]);
                            acc1[j][o] = fmaf(e4[j], b4[o], acc1[j][o]);
                        }
                }
#pragma unroll
                for (int o = 0; o < 4; ++o)
#pragma unroll
                    for (int j = 0; j < 4; ++j) {
                        hidT[(4 * c + o) * 68 + 4 * r + j]      = fmaxf(acc0[j][o], 0.f);
                        hidT[(64 + 4 * c + o) * 68 + 4 * r + j] = fmaxf(acc1[j][o], 0.f);
                    }
            }
            __syncthreads();

            // MLP2: ff = hid W2 + b2; x = e + ff in place into eT
            {
                float acc[4][4];
#pragma unroll
                for (int o = 0; o < 4; ++o) {
                    const float bv = b2[4 * c + o];
#pragma unroll
                    for (int j = 0; j < 4; ++j) acc[j][o] = bv;
                }
                for (int k = 0; k < 128; ++k) {
                    const float4 hv = *(const float4*)&hidT[k * 68 + 4 * r];
                    const float4 wv = *(const float4*)&sW2[k * 68 + 4 * c];
                    const float h4[4] = {hv.x, hv.y, hv.z, hv.w};
                    const float w4[4] = {wv.x, wv.y, wv.z, wv.w};
#pragma unroll
                    for (int j = 0; j < 4; ++j)
#pragma unroll
                        for (int o = 0; o < 4; ++o)
                            acc[j][o] = fmaf(h4[j], w4[o], acc[j][o]);
                }
#pragma unroll
                for (int o = 0; o < 4; ++o)
#pragma unroll
                    for (int j = 0; j < 4; ++j)
                        eT[(4 * c + o) * 68 + (4 * r + j)] += acc[j][o];
            }
            __syncthreads();

            // LN stats
            {
                const int tk = t & 63, p = t >> 6;
                float sv = 0.f, q = 0.f;
#pragma unroll
                for (int i = 0; i < 16; ++i) {
                    const float x = eT[(16 * p + i) * 68 + tk];
                    sv += x;
                    q = fmaf(x, x, q);
                }
                red1[p * 66 + tk] = sv;
                red2[p * 66 + tk] = q;
            }
            __syncthreads();
            if (t < 64) {
                const float sv = ((red1[0 * 66 + t] + red1[1 * 66 + t]) + (red1[2 * 66 + t] + red1[3 * 66 + t]));
                const float qq = ((red2[0 * 66 + t] + red2[1 * 66 + t]) + (red2[2 * 66 + t] + red2[3 * 66 + t]));
                const float mu  = sv * (1.0f / 64.0f);
                const float var = qq * (1.0f / 64.0f) - mu * mu;
                smu[t]   = mu;
                srstd[t] = 1.0f / sqrtf(var + LN_EPS);
            }
            __syncthreads();

            // normalize, round bf16, store rounded f32 into hrows; hh over
            // ROUNDED values; block (b,0) tile 1 token 63 exports q (bf16)
            {
                const int tk = t >> 2, p = t & 3;
                const float mu = smu[tk], rstd = srstd[tk];
                const int lrow = 64 * it + tk;
                float hh = 0.f;
#pragma unroll
                for (int i2 = 0; i2 < 8; ++i2) {
                    const int d = 16 * p + 2 * i2;
                    const float x0 = eT[(d + 0) * 68 + tk];
                    const float x1 = eT[(d + 1) * 68 + tk];
                    const float o0 = (x0 - mu) * rstd * gamma[d + 0] + beta[d + 0];
                    const float o1 = (x1 - mu) * rstd * gamma[d + 1] + beta[d + 1];
                    const u16 r0 = f2bf(o0), r1 = f2bf(o1);
                    const float q0f = bf2f(r0), q1f = bf2f(r1);
                    hh = fmaf(q0f, q0f, hh);
                    hh = fmaf(q1f, q1f, hh);
                    hrows[lrow * 68 + d]     = q0f;
                    hrows[lrow * 68 + d + 1] = q1f;
                    if (s == 0 && lrow == 127) {   // token 2047: export q
                        q_ws[b * 64 + d]     = r0;
                        q_ws[b * 64 + d + 1] = r1;
                    }
                }
                red1[p * 66 + tk] = hh;
            }
            __syncthreads();
            if (t < 64) {
                const float hh = ((red1[0 * 66 + t] + red1[1 * 66 + t]) + (red1[2 * 66 + t] + red1[3 * 66 + t]));
                invd_l[64 * it + t] = 1.0f / (hh + D_EPS);
            }
        }
    }
    __syncthreads();

    // zero the sigma=0 padded key (row 127 = token 2047, only segment 0)
    if (s == 0 && t < 64) hrows[127 * 68 + t] = 0.f;

    // ======================= Phase B: compose =============================
    {
        float* S     = (float*)(smem + C_S);
        float* V     = (float*)(smem + C_V);
        float* Bm    = (float*)(smem + C_BM);
        float* Z     = (float*)(smem + C_Z);
        float* Gm    = (float*)(smem + C_GM);
        float* ivd_s = (float*)(smem + C_IVD);

        // init S = I, V = 0
        for (int idx = t; idx < 64 * 64; idx += 256) {
            const int m = idx >> 6, n = idx & 63;
            S[m * 68 + n] = (m == n) ? 1.0f : 0.0f;
            V[m * 68 + n] = 0.0f;
        }

        for (int cc = 0; cc < CPS; ++cc) {
            const int base = 127 - 16 * cc;   // hrows row of solve-slot j is base-j
            __syncthreads();   // init / previous chunk reads done

            if (t < 16) ivd_s[t] = invd_l[base - t];
            __syncthreads();

            // Gram: Gm[i][j] = (k_i . k_j) * ivd_j, i > j
            {
                const int i = t >> 4, j = t & 15;
                if (i > j) {
                    const float* ra = &hrows[(base - i) * 68];
                    const float* rb = &hrows[(base - j) * 68];
                    float acc = 0.f;
#pragma unroll
                    for (int m = 0; m < 64; m += 4) {
                        const float4 a  = *(const float4*)&ra[m];
                        const float4 bb = *(const float4*)&rb[m];
                        acc += a.x * bb.x + a.y * bb.y + a.z * bb.z + a.w * bb.w;
                    }
                    Gm[i * 17 + j] = acc * ivd_s[j];
                }
            }
            __syncthreads();

            // B: forward substitution L B = K (wave 0)
            if (t < 64) {
                const int n = t;
                float Breg[16];
#pragma unroll
                for (int i = 0; i < 16; ++i) {
                    float acc = hrows[(base - i) * 68 + n];
#pragma unroll
                    for (int j = 0; j < 16; ++j)
                        if (j < i) acc = fmaf(-Gm[i * 17 + j], Breg[j], acc);
                    Breg[i] = acc;
                    Bm[i * 68 + n] = acc;
                }
            }
            __syncthreads();

            // Z = B S
            {
                const int i  = t & 15;
                const int n0 = (t >> 4) * 4;
                float4 z = make_float4(0.f, 0.f, 0.f, 0.f);
#pragma unroll
                for (int mq = 0; mq < 16; ++mq) {
                    const float4 bq = *(const float4*)&Bm[i * 68 + mq * 4];
                    const float4 s0 = *(const float4*)&S[(mq * 4 + 0) * 68 + n0];
                    const float4 s1 = *(const float4*)&S[(mq * 4 + 1) * 68 + n0];
                    const float4 s2 = *(const float4*)&S[(mq * 4 + 2) * 68 + n0];
                    const float4 s3 = *(const float4*)&S[(mq * 4 + 3) * 68 + n0];
                    z.x = fmaf(bq.x, s0.x, fmaf(bq.y, s1.x, fmaf(bq.z, s2.x, fmaf(bq.w, s3.x, z.x))));
                    z.y = fmaf(bq.x, s0.y, fmaf(bq.y, s1.y, fmaf(bq.z, s2.y, fmaf(bq.w, s3.y, z.y))));
                    z.z = fmaf(bq.x, s0.z, fmaf(bq.y, s1.z, fmaf(bq.z, s2.z, fmaf(bq.w, s3.z, z.z))));
                    z.w = fmaf(bq.x, s0.w, fmaf(bq.y, s1.w, fmaf(bq.z, s2.w, fmaf(bq.w, s3.w, z.w))));
                }
                *(float4*)&Z[i * 68 + n0] = z;
            }
            __syncthreads();

            // S -= K^T (ivd_j * Z) ; V += K^T Z   (ztq inline)
            {
                const int n0 = (t & 15) * 4;
                const int mh = t >> 4;
                float iv16[16];
#pragma unroll
                for (int q4 = 0; q4 < 4; ++q4) {
                    const float4 v4 = *(const float4*)&ivd_s[4 * q4];
                    iv16[4*q4+0] = v4.x; iv16[4*q4+1] = v4.y;
                    iv16[4*q4+2] = v4.z; iv16[4*q4+3] = v4.w;
                }
                float4 sacc[4], vacc[4];
#pragma unroll
                for (int p = 0; p < 4; ++p) {
                    sacc[p] = *(float4*)&S[(mh + 16 * p) * 68 + n0];
                    vacc[p] = *(float4*)&V[(mh + 16 * p) * 68 + n0];
                }
#pragma unroll
                for (int j = 0; j < 16; ++j) {
                    const float4 zq = *(const float4*)&Z[j * 68 + n0];
                    const float iv = iv16[j];
                    float4 ztq;
                    ztq.x = zq.x * iv; ztq.y = zq.y * iv;
                    ztq.z = zq.z * iv; ztq.w = zq.w * iv;
                    const float* kr = &hrows[(base - j) * 68];
                    const float k0 = kr[mh];
                    const float k1 = kr[mh + 16];
                    const float k2 = kr[mh + 32];
                    const float k3 = kr[mh + 48];
                    vacc[0].x = fmaf(k0, zq.x, vacc[0].x); vacc[0].y = fmaf(k0, zq.y, vacc[0].y);
                    vacc[0].z = fmaf(k0, zq.z, vacc[0].z); vacc[0].w = fmaf(k0, zq.w, vacc[0].w);
                    vacc[1].x = fmaf(k1, zq.x, vacc[1].x); vacc[1].y = fmaf(k1, zq.y, vacc[1].y);
                    vacc[1].z = fmaf(k1, zq.z, vacc[1].z); vacc[1].w = fmaf(k1, zq.w, vacc[1].w);
                    vacc[2].x = fmaf(k2, zq.x, vacc[2].x); vacc[2].y = fmaf(k2, zq.y, vacc[2].y);
                    vacc[2].z = fmaf(k2, zq.z, vacc[2].z); vacc[2].w = fmaf(k2, zq.w, vacc[2].w);
                    vacc[3].x = fmaf(k3, zq.x, vacc[3].x); vacc[3].y = fmaf(k3, zq.y, vacc[3].y);
                    vacc[3].z = fmaf(k3, zq.z, vacc[3].z); vacc[3].w = fmaf(k3, zq.w, vacc[3].w);
                    sacc[0].x = fmaf(-k0, ztq.x, sacc[0].x); sacc[0].y = fmaf(-k0, ztq.y, sacc[0].y);
                    sacc[0].z = fmaf(-k0, ztq.z, sacc[0].z); sacc[0].w = fmaf(-k0, ztq.w, sacc[0].w);
                    sacc[1].x = fmaf(-k1, ztq.x, sacc[1].x); sacc[1].y = fmaf(-k1, ztq.y, sacc[1].y);
                    sacc[1].z = fmaf(-k1, ztq.z, sacc[1].z); sacc[1].w = fmaf(-k1, ztq.w, sacc[1].w);
                    sacc[2].x = fmaf(-k2, ztq.x, sacc[2].x); sacc[2].y = fmaf(-k2, ztq.y, sacc[2].y);
                    sacc[2].z = fmaf(-k2, ztq.z, sacc[2].z); sacc[2].w = fmaf(-k2, ztq.w, sacc[2].w);
                    sacc[3].x = fmaf(-k3, ztq.x, sacc[3].x); sacc[3].y = fmaf(-k3, ztq.y, sacc[3].y);
                    sacc[3].z = fmaf(-k3, ztq.z, sacc[3].z); sacc[3].w = fmaf(-k3, ztq.w, sacc[3].w);
                }
#pragma unroll
                for (int p = 0; p < 4; ++p) {
                    *(float4*)&S[(mh + 16 * p) * 68 + n0] = sacc[p];
                    *(float4*)&V[(mh + 16 * p) * 68 + n0] = vacc[p];
                }
            }
        }
        __syncthreads();

        // writeback: pk[j*64+i] = pack(bf16(S[i][j]), bf16(V[i][j]))
        u32* pk = PK + ((size_t)(b * NSEG + s) << 12);
        for (int idx = t; idx < 4096; idx += 256) {
            const int j = idx >> 6, i = idx & 63;
            const u32 sb = ((u32)f2bf(S[i * 68 + j])) << 16;
            const u32 vb = (u32)f2bf(V[i * 68 + j]);
            pk[idx] = sb | vb;
        }
    }

    // ============ completion counter: release PK, signal done =============
    __threadfence();            // make PK/q_ws writes device-visible (release)
    __syncthreads();            // all threads' stores issued before the add
    if (t == 0) atomicAdd(counter, 1u);

    if (blockIdx.x >= BATCH) return;

    // ================= Phase C: final (blocks 0..15 only) =================
    {
        if (t == 0) {
            while (__hip_atomic_load(counter, __ATOMIC_ACQUIRE,
                                     __HIP_MEMORY_SCOPE_AGENT) < 256u) {
                __builtin_amdgcn_s_sleep(8);
            }
        }
        __syncthreads();
        __threadfence();        // acquire: PK/q_ws from all blocks now visible

        float* psum = (float*)(smem + F_PSUM);   // [4][72]
        float* rl   = (float*)(smem + F_RL);
        float* cs   = (float*)(smem + F_CS);
        float* rs   = (float*)(smem + F_RS);

        const int fb   = blockIdx.x;     // batch this block finishes
        const int lane = t & 63;
        const int p    = t >> 6;         // wave id = j-slice

        rl[lane] = bf2f(q_ws[fb * 64 + lane]);

        float ctxp = 0.f;
        u32 cur[16], nxt[16];
        {
            const u32* pk0 = PK + ((size_t)(fb * NSEG + 0) << 12);
#pragma unroll
            for (int jj = 0; jj < 16; ++jj)
                cur[jj] = pk0[(p * 16 + jj) * 64 + lane];
        }
        __syncthreads();

        for (int ss = 0; ss < NSEG; ++ss) {
            const int sn = (ss + 1 < NSEG) ? ss + 1 : ss;
            const u32* pkn = PK + ((size_t)(fb * NSEG + sn) << 12);
#pragma unroll
            for (int jj = 0; jj < 16; ++jj)
                nxt[jj] = pkn[(p * 16 + jj) * 64 + lane];

            float accr = 0.f;
#pragma unroll
            for (int jj = 0; jj < 16; ++jj) {
                const u32 pv = cur[jj];
                const float Sv = __uint_as_float(pv & 0xFFFF0000u);
                const float Vv = __uint_as_float(pv << 16);
                const float rj = rl[p * 16 + jj];
                accr = fmaf(Sv, rj, accr);
                ctxp = fmaf(Vv, rj, ctxp);
            }
            psum[p * 72 + lane] = accr;
            __syncthreads();
            const float rn = (psum[0 * 72 + lane] + psum[1 * 72 + lane])
                           + (psum[2 * 72 + lane] + psum[3 * 72 + lane]);
            __syncthreads();
            rl[lane] = rn;

#pragma unroll
            for (int jj = 0; jj < 16; ++jj) cur[jj] = nxt[jj];
        }

        psum[p * 72 + lane] = ctxp;
        __syncthreads();
        if (t < 64)
            cs[t] = (psum[0 * 72 + t] + psum[1 * 72 + t]) + (psum[2 * 72 + t] + psum[3 * 72 + t]);
        __syncthreads();

        float rv = (p == 0) ? br[lane] : 0.f;
#pragma unroll
        for (int i = 0; i < 16; ++i)
            rv = fmaf(cs[p * 16 + i], Wr[(p * 16 + i) * HDIM + lane], rv);
        psum[p * 72 + lane] = rv;
        __syncthreads();
        if (t < 64)
            rs[t] = (psum[0 * 72 + t] + psum[1 * 72 + t]) + (psum[2 * 72 + t] + psum[3 * 72 + t]);
        __syncthreads();

        float ov = (p == 0) ? bo[lane] : 0.f;
#pragma unroll
        for (int i = 0; i < 16; ++i)
            ov = fmaf(rs[p * 16 + i], Wo[(p * 16 + i) * HDIM + lane], ov);
        psum[p * 72 + lane] = ov;
        __syncthreads();
        if (t < 64)
            out[(size_t)fb * HDIM + t] = (psum[0 * 72 + t] + psum[1 * 72 + t]) + (psum[2 * 72 + t] + psum[3 * 72 + t]);
    }
}

// ---------------------------------------------------------------------------
extern "C" void kernel_launch(void* const* d_in, const int* in_sizes, int n_in,
                              void* d_out, int out_size, void* d_ws, size_t ws_size,
                              hipStream_t stream)
{
    const int*   seq   = (const int*)  d_in[0];
    const float* embed = (const float*)d_in[1];
    const float* W1    = (const float*)d_in[2];
    const float* b1    = (const float*)d_in[3];
    const float* W2    = (const float*)d_in[4];
    const float* b2    = (const float*)d_in[5];
    const float* gamma = (const float*)d_in[6];
    const float* beta  = (const float*)d_in[7];
    const float* Wr    = (const float*)d_in[8];
    const float* br    = (const float*)d_in[9];
    const float* Wo    = (const float*)d_in[10];
    const float* bo    = (const float*)d_in[11];

    u32* pk_ws   = (u32*)d_ws;                                  // 4 MB
    u16* q_ws    = (u16*)(pk_ws + (size_t)BATCH * NSEG * 4096); // 2 KB
    u32* counter = (u32*)(q_ws + BATCH * HDIM);                 // 4 B (aligned)
    float* outp  = (float*)d_out;

    hipMemsetAsync(counter, 0, sizeof(u32), stream);
    hipLaunchKernelGGL(fused_kernel, dim3(BATCH * NSEG), dim3(256), 0, stream,
                       seq, embed, W1, b1, W2, b2, gamma, beta,
                       Wr, br, Wo, bo, pk_ws, q_ws, counter, outp);
}

// Round 13
// 142.740 us; speedup vs baseline: 1.1675x; 1.1675x over previous
//
#include <hip/hip_runtime.h>

// Problem constants
#define HDIM 64
#define LSEQ 2048
#define BATCH 16
#define LN_EPS 1e-5f
#define D_EPS 1e-6f
#define NSEG 16      // segments per batch
#define CPS 8        // chunks per segment (16 tokens each) -> 128 tokens/block

typedef unsigned short u16;
typedef unsigned int   u32;

__device__ __forceinline__ float bf2f(u16 v) {
    return __uint_as_float(((u32)v) << 16);
}
__device__ __forceinline__ u16 f2bf(float f) {   // round-to-nearest-even
    u32 u = __float_as_uint(f);
    return (u16)((u + 0x7FFFu + ((u >> 16) & 1u)) >> 16);
}

// ---------------- shared-memory overlay (bytes) ----------------
// Phase A scratch (dead after preprocess):
#define P_SW1   0        // f32[64*132]  33792
#define P_SW2   33792    // f32[128*68]  34816
#define P_ET    68608    // f32[64*68]   17408
#define P_HIDT  86016    // f32[128*68]  34816
#define P_RED1  120832   // f32[8*66]    2112
#define P_RED2  122944   // f32[8*66]    2112
#define P_SMU   125056   // f32[68]      272
#define P_SRSTD 125328   // f32[68]      272
// Persistent across phases A/B:
#define H_ROWS  125600   // f32[128*68]  34816  (bf16-rounded h, row-major)
#define H_INVD  160416   // f32[128]     512
#define SMEM_BYTES 160928   // <= 163840 (160 KiB/CU)
// Compose overlays phase-A scratch:
#define C_S     0        // f32[64*68]   17408
#define C_V     17408    // f32[64*68]   17408
#define C_BM    34816    // f32[16*68]   4352
#define C_Z     39168    // f32[16*68]   4352
#define C_GM    43520    // f32[16*17]   1088
#define C_IVD   44608    // f32[16]      64

// ---------------------------------------------------------------------------
// Kernel A: fused preprocess + segment composition — R13: 512 threads/block
// (2 waves/SIMD vs R11's 1) for latency hiding; per-thread microtiles halved.
// Block = (batch b, segment s) consumes tokens [1920-128s, 2047-128s].
// Per-output accumulation order identical to R11 except LN partial tree.
// ---------------------------------------------------------------------------
__global__ __launch_bounds__(512, 1) void fused_pc_kernel(
    const int* __restrict__ seq, const float* __restrict__ embed,
    const float* __restrict__ W1, const float* __restrict__ b1,
    const float* __restrict__ W2, const float* __restrict__ b2,
    const float* __restrict__ gamma, const float* __restrict__ beta,
    u32* __restrict__ PK, u16* __restrict__ q_ws)
{
    __shared__ __align__(16) char smem[SMEM_BYTES];
    const int t = threadIdx.x;
    const int b = blockIdx.x >> 4;
    const int s = blockIdx.x & 15;
    const int tok0 = 1920 - 128 * s;          // first token of this block

    float* hrows  = (float*)(smem + H_ROWS);
    float* invd_l = (float*)(smem + H_INVD);

    // ======================= Phase A: preprocess ==========================
    {
        float* sW1   = (float*)(smem + P_SW1);
        float* sW2   = (float*)(smem + P_SW2);
        float* eT    = (float*)(smem + P_ET);
        float* hidT  = (float*)(smem + P_HIDT);
        float* red1  = (float*)(smem + P_RED1);
        float* red2  = (float*)(smem + P_RED2);
        float* smu   = (float*)(smem + P_SMU);
        float* srstd = (float*)(smem + P_SRSTD);

        // stage W1 (64x128, stride 132) and W2 (128x64, stride 68) once
        {
            const float4* s1 = (const float4*)W1;   // 2048 float4
#pragma unroll
            for (int q = 0; q < 4; ++q) {
                const int m = t + 512 * q;
                const int row = m >> 5, col = m & 31;
                *(float4*)&sW1[row * 132 + col * 4] = s1[m];
            }
            const float4* s2 = (const float4*)W2;   // 2048 float4
#pragma unroll
            for (int q = 0; q < 4; ++q) {
                const int m = t + 512 * q;
                const int row = m >> 4, col = m & 15;
                *(float4*)&sW2[row * 68 + col * 4] = s2[m];
            }
        }

        for (int it = 0; it < 2; ++it) {
            const int g0 = b * LSEQ + tok0 + 64 * it;   // global token base
            __syncthreads();   // W staging (it=0) / prior tile reads (it=1)

            // stage embeddings transposed: thread (tk = t>>3, p = t&7)
            {
                const int tk = t >> 3, p = t & 7;
                const int v = seq[g0 + tk];
                const float* er = embed + v * HDIM + 8 * p;
#pragma unroll
                for (int q = 0; q < 2; ++q) {
                    const float4 ev = *(const float4*)(er + 4 * q);
                    const int d = 8 * p + 4 * q;
                    eT[(d + 0) * 68 + tk] = ev.x;
                    eT[(d + 1) * 68 + tk] = ev.y;
                    eT[(d + 2) * 68 + tk] = ev.z;
                    eT[(d + 3) * 68 + tk] = ev.w;
                }
            }
            __syncthreads();

            const int r2 = t >> 4;   // token pair: toks 2*r2, 2*r2+1 (0..31)
            const int c  = t & 15;   // out quad

            // MLP1: hid = relu(e W1 + b1); 2 tok x (4+4) outs per thread
            {
                float acc0[2][4], acc1[2][4];
#pragma unroll
                for (int o = 0; o < 4; ++o) {
                    const float bA = b1[4 * c + o];
                    const float bB = b1[64 + 4 * c + o];
#pragma unroll
                    for (int j = 0; j < 2; ++j) { acc0[j][o] = bA; acc1[j][o] = bB; }
                }
                for (int k = 0; k < 64; ++k) {
                    const float2 ev = *(const float2*)&eT[k * 68 + 2 * r2];
                    const float4 wa = *(const float4*)&sW1[k * 132 + 4 * c];
                    const float4 wb = *(const float4*)&sW1[k * 132 + 64 + 4 * c];
                    const float e2[2] = {ev.x, ev.y};
                    const float a4[4] = {wa.x, wa.y, wa.z, wa.w};
                    const float b4[4] = {wb.x, wb.y, wb.z, wb.w};
#pragma unroll
                    for (int j = 0; j < 2; ++j)
#pragma unroll
                        for (int o = 0; o < 4; ++o) {
                            acc0[j][o] = fmaf(e2[j], a4[o], acc0[j][o]);
                            acc1[j][o] = fmaf(e2[j], b4[o], acc1[j][o]);
                        }
                }
#pragma unroll
                for (int o = 0; o < 4; ++o)
#pragma unroll
                    for (int j = 0; j < 2; ++j) {
                        hidT[(4 * c + o) * 68 + 2 * r2 + j]      = fmaxf(acc0[j][o], 0.f);
                        hidT[(64 + 4 * c + o) * 68 + 2 * r2 + j] = fmaxf(acc1[j][o], 0.f);
                    }
            }
            __syncthreads();

            // MLP2: ff = hid W2 + b2; x = e + ff in place into eT
            {
                float acc[2][4];
#pragma unroll
                for (int o = 0; o < 4; ++o) {
                    const float bv = b2[4 * c + o];
#pragma unroll
                    for (int j = 0; j < 2; ++j) acc[j][o] = bv;
                }
                for (int k = 0; k < 128; ++k) {
                    const float2 hv = *(const float2*)&hidT[k * 68 + 2 * r2];
                    const float4 wv = *(const float4*)&sW2[k * 68 + 4 * c];
                    const float h2[2] = {hv.x, hv.y};
                    const float w4[4] = {wv.x, wv.y, wv.z, wv.w};
#pragma unroll
                    for (int j = 0; j < 2; ++j)
#pragma unroll
                        for (int o = 0; o < 4; ++o)
                            acc[j][o] = fmaf(h2[j], w4[o], acc[j][o]);
                }
#pragma unroll
                for (int o = 0; o < 4; ++o)
#pragma unroll
                    for (int j = 0; j < 2; ++j)
                        eT[(4 * c + o) * 68 + (2 * r2 + j)] += acc[j][o];
            }
            __syncthreads();

            // LN stats: thread (tk = t&63, p = t>>6 in 0..7) sums 8 dims
            {
                const int tk = t & 63, p = t >> 6;
                float sv = 0.f, q = 0.f;
#pragma unroll
                for (int i = 0; i < 8; ++i) {
                    const float x = eT[(8 * p + i) * 68 + tk];
                    sv += x;
                    q = fmaf(x, x, q);
                }
                red1[p * 66 + tk] = sv;
                red2[p * 66 + tk] = q;
            }
            __syncthreads();
            if (t < 64) {
                float sv = ((red1[0 * 66 + t] + red1[1 * 66 + t]) + (red1[2 * 66 + t] + red1[3 * 66 + t]))
                         + ((red1[4 * 66 + t] + red1[5 * 66 + t]) + (red1[6 * 66 + t] + red1[7 * 66 + t]));
                float qq = ((red2[0 * 66 + t] + red2[1 * 66 + t]) + (red2[2 * 66 + t] + red2[3 * 66 + t]))
                         + ((red2[4 * 66 + t] + red2[5 * 66 + t]) + (red2[6 * 66 + t] + red2[7 * 66 + t]));
                const float mu  = sv * (1.0f / 64.0f);
                const float var = qq * (1.0f / 64.0f) - mu * mu;
                smu[t]   = mu;
                srstd[t] = 1.0f / sqrtf(var + LN_EPS);
            }
            __syncthreads();

            // normalize, round bf16, store rounded f32 into hrows; hh over
            // ROUNDED values; block (b,0) token 2047 exports q (bf16)
            {
                const int tk = t >> 3, p = t & 7;
                const float mu = smu[tk], rstd = srstd[tk];
                const int lrow = 64 * it + tk;
                float hh = 0.f;
#pragma unroll
                for (int i2 = 0; i2 < 4; ++i2) {
                    const int d = 8 * p + 2 * i2;
                    const float x0 = eT[(d + 0) * 68 + tk];
                    const float x1 = eT[(d + 1) * 68 + tk];
                    const float o0 = (x0 - mu) * rstd * gamma[d + 0] + beta[d + 0];
                    const float o1 = (x1 - mu) * rstd * gamma[d + 1] + beta[d + 1];
                    const u16 r0 = f2bf(o0), r1 = f2bf(o1);
                    const float q0f = bf2f(r0), q1f = bf2f(r1);
                    hh = fmaf(q0f, q0f, hh);
                    hh = fmaf(q1f, q1f, hh);
                    hrows[lrow * 68 + d]     = q0f;
                    hrows[lrow * 68 + d + 1] = q1f;
                    if (s == 0 && lrow == 127) {   // token 2047: export q
                        q_ws[b * 64 + d]     = r0;
                        q_ws[b * 64 + d + 1] = r1;
                    }
                }
                red1[p * 66 + tk] = hh;
            }
            __syncthreads();
            if (t < 64) {
                const float hh = ((red1[0 * 66 + t] + red1[1 * 66 + t]) + (red1[2 * 66 + t] + red1[3 * 66 + t]))
                               + ((red1[4 * 66 + t] + red1[5 * 66 + t]) + (red1[6 * 66 + t] + red1[7 * 66 + t]));
                invd_l[64 * it + t] = 1.0f / (hh + D_EPS);
            }
        }
    }
    __syncthreads();

    // zero the sigma=0 padded key (row 127 = token 2047, only segment 0)
    if (s == 0 && t < 64) hrows[127 * 68 + t] = 0.f;

    // ======================= Phase B: compose =============================
    {
        float* S     = (float*)(smem + C_S);
        float* V     = (float*)(smem + C_V);
        float* Bm    = (float*)(smem + C_BM);
        float* Z     = (float*)(smem + C_Z);
        float* Gm    = (float*)(smem + C_GM);
        float* ivd_s = (float*)(smem + C_IVD);

        // init S = I, V = 0
        for (int idx = t; idx < 64 * 64; idx += 512) {
            const int m = idx >> 6, n = idx & 63;
            S[m * 68 + n] = (m == n) ? 1.0f : 0.0f;
            V[m * 68 + n] = 0.0f;
        }

        for (int cc = 0; cc < CPS; ++cc) {
            const int base = 127 - 16 * cc;   // hrows row of solve-slot j is base-j
            __syncthreads();   // init / previous chunk reads done

            if (t < 16) ivd_s[t] = invd_l[base - t];
            __syncthreads();

            // Gram: Gm[i][j] = (k_i . k_j) * ivd_j, i > j  (threads 0..255)
            if (t < 256) {
                const int i = t >> 4, j = t & 15;
                if (i > j) {
                    const float* ra = &hrows[(base - i) * 68];
                    const float* rb = &hrows[(base - j) * 68];
                    float acc = 0.f;
#pragma unroll
                    for (int m = 0; m < 64; m += 4) {
                        const float4 a  = *(const float4*)&ra[m];
                        const float4 bb = *(const float4*)&rb[m];
                        acc += a.x * bb.x + a.y * bb.y + a.z * bb.z + a.w * bb.w;
                    }
                    Gm[i * 17 + j] = acc * ivd_s[j];
                }
            }
            __syncthreads();

            // B: forward substitution L B = K (wave 0)
            if (t < 64) {
                const int n = t;
                float Breg[16];
#pragma unroll
                for (int i = 0; i < 16; ++i) {
                    float acc = hrows[(base - i) * 68 + n];
#pragma unroll
                    for (int j = 0; j < 16; ++j)
                        if (j < i) acc = fmaf(-Gm[i * 17 + j], Breg[j], acc);
                    Breg[i] = acc;
                    Bm[i * 68 + n] = acc;
                }
            }
            __syncthreads();

            // Z = B S : thread = (i = t&15, col pair n2 = (t>>4)*2)
            {
                const int i  = t & 15;
                const int n2 = (t >> 4) * 2;
                float zx = 0.f, zy = 0.f;
#pragma unroll
                for (int mq = 0; mq < 16; ++mq) {
                    const float4 bq = *(const float4*)&Bm[i * 68 + mq * 4];
                    const float2 s0 = *(const float2*)&S[(mq * 4 + 0) * 68 + n2];
                    const float2 s1 = *(const float2*)&S[(mq * 4 + 1) * 68 + n2];
                    const float2 s2 = *(const float2*)&S[(mq * 4 + 2) * 68 + n2];
                    const float2 s3 = *(const float2*)&S[(mq * 4 + 3) * 68 + n2];
                    zx = fmaf(bq.x, s0.x, fmaf(bq.y, s1.x, fmaf(bq.z, s2.x, fmaf(bq.w, s3.x, zx))));
                    zy = fmaf(bq.x, s0.y, fmaf(bq.y, s1.y, fmaf(bq.z, s2.y, fmaf(bq.w, s3.y, zy))));
                }
                float2 z2; z2.x = zx; z2.y = zy;
                *(float2*)&Z[i * 68 + n2] = z2;
            }
            __syncthreads();

            // S -= K^T (ivd_j * Z) ; V += K^T Z : thread = (n0, mh in 0..31),
            // rows mh and mh+32.
            {
                const int n0 = (t & 15) * 4;
                const int mh = t >> 4;          // 0..31
                float iv16[16];
#pragma unroll
                for (int q4 = 0; q4 < 4; ++q4) {
                    const float4 v4 = *(const float4*)&ivd_s[4 * q4];
                    iv16[4*q4+0] = v4.x; iv16[4*q4+1] = v4.y;
                    iv16[4*q4+2] = v4.z; iv16[4*q4+3] = v4.w;
                }
                float4 sacc[2], vacc[2];
#pragma unroll
                for (int p = 0; p < 2; ++p) {
                    sacc[p] = *(float4*)&S[(mh + 32 * p) * 68 + n0];
                    vacc[p] = *(float4*)&V[(mh + 32 * p) * 68 + n0];
                }
#pragma unroll
                for (int j = 0; j < 16; ++j) {
                    const float4 zq = *(const float4*)&Z[j * 68 + n0];
                    const float iv = iv16[j];
                    float4 ztq;
                    ztq.x = zq.x * iv; ztq.y = zq.y * iv;
                    ztq.z = zq.z * iv; ztq.w = zq.w * iv;
                    const float* kr = &hrows[(base - j) * 68];
                    const float k0 = kr[mh];
                    const float k1 = kr[mh + 32];
                    vacc[0].x = fmaf(k0, zq.x, vacc[0].x); vacc[0].y = fmaf(k0, zq.y, vacc[0].y);
                    vacc[0].z = fmaf(k0, zq.z, vacc[0].z); vacc[0].w = fmaf(k0, zq.w, vacc[0].w);
                    vacc[1].x = fmaf(k1, zq.x, vacc[1].x); vacc[1].y = fmaf(k1, zq.y, vacc[1].y);
                    vacc[1].z = fmaf(k1, zq.z, vacc[1].z); vacc[1].w = fmaf(k1, zq.w, vacc[1].w);
                    sacc[0].x = fmaf(-k0, ztq.x, sacc[0].x); sacc[0].y = fmaf(-k0, ztq.y, sacc[0].y);
                    sacc[0].z = fmaf(-k0, ztq.z, sacc[0].z); sacc[0].w = fmaf(-k0, ztq.w, sacc[0].w);
                    sacc[1].x = fmaf(-k1, ztq.x, sacc[1].x); sacc[1].y = fmaf(-k1, ztq.y, sacc[1].y);
                    sacc[1].z = fmaf(-k1, ztq.z, sacc[1].z); sacc[1].w = fmaf(-k1, ztq.w, sacc[1].w);
                }
#pragma unroll
                for (int p = 0; p < 2; ++p) {
                    *(float4*)&S[(mh + 32 * p) * 68 + n0] = sacc[p];
                    *(float4*)&V[(mh + 32 * p) * 68 + n0] = vacc[p];
                }
            }
        }
        __syncthreads();

        // writeback: pk[j*64+i] = pack(bf16(S[i][j]), bf16(V[i][j]))
        u32* pk = PK + ((size_t)(b * NSEG + s) << 12);
        for (int idx = t; idx < 4096; idx += 512) {
            const int j = idx >> 6, i = idx & 63;
            const u32 sb = ((u32)f2bf(S[i * 68 + j])) << 16;
            const u32 vb = (u32)f2bf(V[i * 68 + j]);
            pk[idx] = sb | vb;
        }
    }
}

// ---------------------------------------------------------------------------
// Kernel B: serial segment pass + output projection (R11 structure, NSEG=16).
// 16 blocks x 256 threads (4 waves/batch), next-segment loads prefetched.
// ---------------------------------------------------------------------------
__global__ __launch_bounds__(256, 1) void final_kernel(
    const u16* __restrict__ q_ws, const u32* __restrict__ PK,
    const float* __restrict__ Wr, const float* __restrict__ br,
    const float* __restrict__ Wo, const float* __restrict__ bo,
    float* __restrict__ out)
{
    const int b    = blockIdx.x;
    const int t    = threadIdx.x;
    const int lane = t & 63;
    const int p    = t >> 6;         // wave id = j-slice

    __shared__ float psum[4][72];
    __shared__ float rl[64];
    __shared__ float cs[64], rs[64];

    rl[lane] = bf2f(q_ws[b * 64 + lane]);

    float ctxp = 0.f;
    u32 cur[16], nxt[16];
    {
        const u32* pk0 = PK + ((size_t)(b * NSEG + 0) << 12);
#pragma unroll
        for (int jj = 0; jj < 16; ++jj)
            cur[jj] = pk0[(p * 16 + jj) * 64 + lane];
    }
    __syncthreads();

    for (int s = 0; s < NSEG; ++s) {
        const int sn = (s + 1 < NSEG) ? s + 1 : s;
        const u32* pkn = PK + ((size_t)(b * NSEG + sn) << 12);
#pragma unroll
        for (int jj = 0; jj < 16; ++jj)
            nxt[jj] = pkn[(p * 16 + jj) * 64 + lane];

        float accr = 0.f;
#pragma unroll
        for (int jj = 0; jj < 16; ++jj) {
            const u32 pv = cur[jj];
            const float Sv = __uint_as_float(pv & 0xFFFF0000u);
            const float Vv = __uint_as_float(pv << 16);
            const float rj = rl[p * 16 + jj];
            accr = fmaf(Sv, rj, accr);
            ctxp = fmaf(Vv, rj, ctxp);
        }
        psum[p][lane] = accr;
        __syncthreads();
        const float rn = (psum[0][lane] + psum[1][lane]) + (psum[2][lane] + psum[3][lane]);
        __syncthreads();
        rl[lane] = rn;

#pragma unroll
        for (int jj = 0; jj < 16; ++jj) cur[jj] = nxt[jj];
    }

    psum[p][lane] = ctxp;
    __syncthreads();
    if (t < 64)
        cs[t] = (psum[0][t] + psum[1][t]) + (psum[2][t] + psum[3][t]);
    __syncthreads();

    float rv = (p == 0) ? br[lane] : 0.f;
#pragma unroll
    for (int i = 0; i < 16; ++i)
        rv = fmaf(cs[p * 16 + i], Wr[(p * 16 + i) * HDIM + lane], rv);
    psum[p][lane] = rv;
    __syncthreads();
    if (t < 64)
        rs[t] = (psum[0][t] + psum[1][t]) + (psum[2][t] + psum[3][t]);
    __syncthreads();

    float ov = (p == 0) ? bo[lane] : 0.f;
#pragma unroll
    for (int i = 0; i < 16; ++i)
        ov = fmaf(rs[p * 16 + i], Wo[(p * 16 + i) * HDIM + lane], ov);
    psum[p][lane] = ov;
    __syncthreads();
    if (t < 64)
        out[(size_t)b * HDIM + t] = (psum[0][t] + psum[1][t]) + (psum[2][t] + psum[3][t]);
}

// ---------------------------------------------------------------------------
extern "C" void kernel_launch(void* const* d_in, const int* in_sizes, int n_in,
                              void* d_out, int out_size, void* d_ws, size_t ws_size,
                              hipStream_t stream)
{
    const int*   seq   = (const int*)  d_in[0];
    const float* embed = (const float*)d_in[1];
    const float* W1    = (const float*)d_in[2];
    const float* b1    = (const float*)d_in[3];
    const float* W2    = (const float*)d_in[4];
    const float* b2    = (const float*)d_in[5];
    const float* gamma = (const float*)d_in[6];
    const float* beta  = (const float*)d_in[7];
    const float* Wr    = (const float*)d_in[8];
    const float* br    = (const float*)d_in[9];
    const float* Wo    = (const float*)d_in[10];
    const float* bo    = (const float*)d_in[11];

    u32* pk_ws = (u32*)d_ws;                                  // 4 MB
    u16* q_ws  = (u16*)(pk_ws + (size_t)BATCH * NSEG * 4096); // 2 KB
    float* outp = (float*)d_out;

    hipLaunchKernelGGL(fused_pc_kernel, dim3(BATCH * NSEG), dim3(512), 0, stream,
                       seq, embed, W1, b1, W2, b2, gamma, beta, pk_ws, q_ws);
    hipLaunchKernelGGL(final_kernel, dim3(BATCH), dim3(256), 0, stream,
                       q_ws, pk_ws, Wr, br, Wo, bo, outp);
}

// Round 14
// 140.975 us; speedup vs baseline: 1.1821x; 1.0125x over previous
//
#include <hip/hip_runtime.h>

// Problem constants
#define HDIM 64
#define LSEQ 2048
#define BATCH 16
#define LN_EPS 1e-5f
#define D_EPS 1e-6f
#define NSEG 16      // segments per batch
#define CPS 8        // chunks per segment (16 tokens each) -> 128 tokens/block

typedef unsigned short u16;
typedef unsigned int   u32;

__device__ __forceinline__ float bf2f(u16 v) {
    return __uint_as_float(((u32)v) << 16);
}
__device__ __forceinline__ u16 f2bf(float f) {   // round-to-nearest-even
    u32 u = __float_as_uint(f);
    return (u16)((u + 0x7FFFu + ((u >> 16) & 1u)) >> 16);
}

// ---------------- shared-memory overlay (bytes) ----------------
// Phase A scratch (dead after preprocess):
#define P_SW1   0        // f32[64*132]  33792
#define P_SW2   33792    // f32[128*68]  34816
#define P_ET    68608    // f32[64*68]   17408
#define P_HIDT  86016    // f32[128*68]  34816
#define P_RED1  120832   // f32[4*66]    1056
#define P_RED2  121888   // f32[4*66]    1056
#define P_SMU   122944   // f32[68]      272
#define P_SRSTD 123216   // f32[68]      272
// Persistent across phases A/B:
#define H_ROWS  123488   // f32[128*68]  34816  (bf16-rounded h, row-major)
#define H_INVD  158304   // f32[128]     512
#define SMEM_BYTES 158816
// Compose overlays phase-A scratch:
#define C_S     0        // f32[64*68]   17408
#define C_V     17408    // f32[64*68]   17408
#define C_BM    34816    // f32[16*68]   4352
#define C_Z     39168    // f32[16*68]   4352
#define C_GM    43520    // f32[16*17]   1088

// ---------------------------------------------------------------------------
// Kernel A: fused preprocess + segment composition (R11 structure; R14: ivd
// LDS staging removed — Gram/update read invd_l directly, one fewer barrier
// per chunk; all arithmetic values bit-identical to R11).
// Block = (batch b, segment s) consumes tokens [1920-128s, 2047-128s].
// ---------------------------------------------------------------------------
__global__ __launch_bounds__(256, 1) void fused_pc_kernel(
    const int* __restrict__ seq, const float* __restrict__ embed,
    const float* __restrict__ W1, const float* __restrict__ b1,
    const float* __restrict__ W2, const float* __restrict__ b2,
    const float* __restrict__ gamma, const float* __restrict__ beta,
    u32* __restrict__ PK, u16* __restrict__ q_ws)
{
    __shared__ __align__(16) char smem[SMEM_BYTES];
    const int t = threadIdx.x;
    const int b = blockIdx.x >> 4;
    const int s = blockIdx.x & 15;
    const int tok0 = 1920 - 128 * s;          // first token of this block

    float* hrows  = (float*)(smem + H_ROWS);
    float* invd_l = (float*)(smem + H_INVD);

    // ======================= Phase A: preprocess ==========================
    {
        float* sW1   = (float*)(smem + P_SW1);
        float* sW2   = (float*)(smem + P_SW2);
        float* eT    = (float*)(smem + P_ET);
        float* hidT  = (float*)(smem + P_HIDT);
        float* red1  = (float*)(smem + P_RED1);
        float* red2  = (float*)(smem + P_RED2);
        float* smu   = (float*)(smem + P_SMU);
        float* srstd = (float*)(smem + P_SRSTD);

        // stage W1 (64x128, stride 132) and W2 (128x64, stride 68) once
        {
            const float4* s1 = (const float4*)W1;   // 2048 float4
#pragma unroll
            for (int q = 0; q < 8; ++q) {
                const int m = t + 256 * q;
                const int row = m >> 5, col = m & 31;
                *(float4*)&sW1[row * 132 + col * 4] = s1[m];
            }
            const float4* s2 = (const float4*)W2;   // 2048 float4
#pragma unroll
            for (int q = 0; q < 8; ++q) {
                const int m = t + 256 * q;
                const int row = m >> 4, col = m & 15;
                *(float4*)&sW2[row * 68 + col * 4] = s2[m];
            }
        }

        for (int it = 0; it < 2; ++it) {
            const int g0 = b * LSEQ + tok0 + 64 * it;   // global token base
            __syncthreads();   // W staging (it=0) / prior tile reads (it=1)

            // stage embeddings transposed: thread (tk = t>>2, p = t&3)
            {
                const int tk = t >> 2, p = t & 3;
                const int v = seq[g0 + tk];
                const float* er = embed + v * HDIM + 16 * p;
#pragma unroll
                for (int q = 0; q < 4; ++q) {
                    const float4 ev = *(const float4*)(er + 4 * q);
                    const int d = 16 * p + 4 * q;
                    eT[(d + 0) * 68 + tk] = ev.x;
                    eT[(d + 1) * 68 + tk] = ev.y;
                    eT[(d + 2) * 68 + tk] = ev.z;
                    eT[(d + 3) * 68 + tk] = ev.w;
                }
            }
            __syncthreads();

            const int r = t >> 4;   // token quad
            const int c = t & 15;   // out quad

            // MLP1: hid = relu(e W1 + b1)
            {
                float acc0[4][4], acc1[4][4];
#pragma unroll
                for (int o = 0; o < 4; ++o) {
                    const float bA = b1[4 * c + o];
                    const float bB = b1[64 + 4 * c + o];
#pragma unroll
                    for (int j = 0; j < 4; ++j) { acc0[j][o] = bA; acc1[j][o] = bB; }
                }
                for (int k = 0; k < 64; ++k) {
                    const float4 ev = *(const float4*)&eT[k * 68 + 4 * r];
                    const float4 wa = *(const float4*)&sW1[k * 132 + 4 * c];
                    const float4 wb = *(const float4*)&sW1[k * 132 + 64 + 4 * c];
                    const float e4[4] = {ev.x, ev.y, ev.z, ev.w};
                    const float a4[4] = {wa.x, wa.y, wa.z, wa.w};
                    const float b4[4] = {wb.x, wb.y, wb.z, wb.w};
#pragma unroll
                    for (int j = 0; j < 4; ++j)
#pragma unroll
                        for (int o = 0; o < 4; ++o) {
                            acc0[j][o] = fmaf(e4[j], a4[o], acc0[j][o]);
                            acc1[j][o] = fmaf(e4[j], b4[o], acc1[j][o]);
                        }
                }
#pragma unroll
                for (int o = 0; o < 4; ++o)
#pragma unroll
                    for (int j = 0; j < 4; ++j) {
                        hidT[(4 * c + o) * 68 + 4 * r + j]      = fmaxf(acc0[j][o], 0.f);
                        hidT[(64 + 4 * c + o) * 68 + 4 * r + j] = fmaxf(acc1[j][o], 0.f);
                    }
            }
            __syncthreads();

            // MLP2: ff = hid W2 + b2; x = e + ff in place into eT
            {
                float acc[4][4];
#pragma unroll
                for (int o = 0; o < 4; ++o) {
                    const float bv = b2[4 * c + o];
#pragma unroll
                    for (int j = 0; j < 4; ++j) acc[j][o] = bv;
                }
                for (int k = 0; k < 128; ++k) {
                    const float4 hv = *(const float4*)&hidT[k * 68 + 4 * r];
                    const float4 wv = *(const float4*)&sW2[k * 68 + 4 * c];
                    const float h4[4] = {hv.x, hv.y, hv.z, hv.w};
                    const float w4[4] = {wv.x, wv.y, wv.z, wv.w};
#pragma unroll
                    for (int j = 0; j < 4; ++j)
#pragma unroll
                        for (int o = 0; o < 4; ++o)
                            acc[j][o] = fmaf(h4[j], w4[o], acc[j][o]);
                }
#pragma unroll
                for (int o = 0; o < 4; ++o)
#pragma unroll
                    for (int j = 0; j < 4; ++j)
                        eT[(4 * c + o) * 68 + (4 * r + j)] += acc[j][o];
            }
            __syncthreads();

            // LN stats
            {
                const int tk = t & 63, p = t >> 6;
                float sv = 0.f, q = 0.f;
#pragma unroll
                for (int i = 0; i < 16; ++i) {
                    const float x = eT[(16 * p + i) * 68 + tk];
                    sv += x;
                    q = fmaf(x, x, q);
                }
                red1[p * 66 + tk] = sv;
                red2[p * 66 + tk] = q;
            }
            __syncthreads();
            if (t < 64) {
                const float sv = ((red1[0 * 66 + t] + red1[1 * 66 + t]) + (red1[2 * 66 + t] + red1[3 * 66 + t]));
                const float qq = ((red2[0 * 66 + t] + red2[1 * 66 + t]) + (red2[2 * 66 + t] + red2[3 * 66 + t]));
                const float mu  = sv * (1.0f / 64.0f);
                const float var = qq * (1.0f / 64.0f) - mu * mu;
                smu[t]   = mu;
                srstd[t] = 1.0f / sqrtf(var + LN_EPS);
            }
            __syncthreads();

            // normalize, round bf16, store rounded f32 into hrows; hh over
            // ROUNDED values; block (b,0) token 2047 exports q (bf16)
            {
                const int tk = t >> 2, p = t & 3;
                const float mu = smu[tk], rstd = srstd[tk];
                const int lrow = 64 * it + tk;
                float hh = 0.f;
#pragma unroll
                for (int i2 = 0; i2 < 8; ++i2) {
                    const int d = 16 * p + 2 * i2;
                    const float x0 = eT[(d + 0) * 68 + tk];
                    const float x1 = eT[(d + 1) * 68 + tk];
                    const float o0 = (x0 - mu) * rstd * gamma[d + 0] + beta[d + 0];
                    const float o1 = (x1 - mu) * rstd * gamma[d + 1] + beta[d + 1];
                    const u16 r0 = f2bf(o0), r1 = f2bf(o1);
                    const float q0f = bf2f(r0), q1f = bf2f(r1);
                    hh = fmaf(q0f, q0f, hh);
                    hh = fmaf(q1f, q1f, hh);
                    hrows[lrow * 68 + d]     = q0f;
                    hrows[lrow * 68 + d + 1] = q1f;
                    if (s == 0 && lrow == 127) {   // token 2047: export q
                        q_ws[b * 64 + d]     = r0;
                        q_ws[b * 64 + d + 1] = r1;
                    }
                }
                red1[p * 66 + tk] = hh;
            }
            __syncthreads();
            if (t < 64) {
                const float hh = ((red1[0 * 66 + t] + red1[1 * 66 + t]) + (red1[2 * 66 + t] + red1[3 * 66 + t]));
                invd_l[64 * it + t] = 1.0f / (hh + D_EPS);
            }
        }
    }
    __syncthreads();

    // zero the sigma=0 padded key (row 127 = token 2047, only segment 0)
    if (s == 0 && t < 64) hrows[127 * 68 + t] = 0.f;

    // ======================= Phase B: compose =============================
    {
        float* S  = (float*)(smem + C_S);
        float* V  = (float*)(smem + C_V);
        float* Bm = (float*)(smem + C_BM);
        float* Z  = (float*)(smem + C_Z);
        float* Gm = (float*)(smem + C_GM);

        // init S = I, V = 0
        for (int idx = t; idx < 64 * 64; idx += 256) {
            const int m = idx >> 6, n = idx & 63;
            S[m * 68 + n] = (m == n) ? 1.0f : 0.0f;
            V[m * 68 + n] = 0.0f;
        }

        for (int cc = 0; cc < CPS; ++cc) {
            const int base = 127 - 16 * cc;   // hrows row of solve-slot j is base-j
            __syncthreads();   // init / previous chunk reads done

            // Gram: Gm[i][j] = (k_i . k_j) * invd[base-j], i > j
            {
                const int i = t >> 4, j = t & 15;
                if (i > j) {
                    const float* ra = &hrows[(base - i) * 68];
                    const float* rb = &hrows[(base - j) * 68];
                    float acc = 0.f;
#pragma unroll
                    for (int m = 0; m < 64; m += 4) {
                        const float4 a  = *(const float4*)&ra[m];
                        const float4 bb = *(const float4*)&rb[m];
                        acc += a.x * bb.x + a.y * bb.y + a.z * bb.z + a.w * bb.w;
                    }
                    Gm[i * 17 + j] = acc * invd_l[base - j];
                }
            }
            __syncthreads();

            // B: forward substitution L B = K (wave 0)
            if (t < 64) {
                const int n = t;
                float Breg[16];
#pragma unroll
                for (int i = 0; i < 16; ++i) {
                    float acc = hrows[(base - i) * 68 + n];
#pragma unroll
                    for (int j = 0; j < 16; ++j)
                        if (j < i) acc = fmaf(-Gm[i * 17 + j], Breg[j], acc);
                    Breg[i] = acc;
                    Bm[i * 68 + n] = acc;
                }
            }
            __syncthreads();

            // Z = B S
            {
                const int i  = t & 15;
                const int n0 = (t >> 4) * 4;
                float4 z = make_float4(0.f, 0.f, 0.f, 0.f);
#pragma unroll
                for (int mq = 0; mq < 16; ++mq) {
                    const float4 bq = *(const float4*)&Bm[i * 68 + mq * 4];
                    const float4 s0 = *(const float4*)&S[(mq * 4 + 0) * 68 + n0];
                    const float4 s1 = *(const float4*)&S[(mq * 4 + 1) * 68 + n0];
                    const float4 s2 = *(const float4*)&S[(mq * 4 + 2) * 68 + n0];
                    const float4 s3 = *(const float4*)&S[(mq * 4 + 3) * 68 + n0];
                    z.x = fmaf(bq.x, s0.x, fmaf(bq.y, s1.x, fmaf(bq.z, s2.x, fmaf(bq.w, s3.x, z.x))));
                    z.y = fmaf(bq.x, s0.y, fmaf(bq.y, s1.y, fmaf(bq.z, s2.y, fmaf(bq.w, s3.y, z.y))));
                    z.z = fmaf(bq.x, s0.z, fmaf(bq.y, s1.z, fmaf(bq.z, s2.z, fmaf(bq.w, s3.z, z.z))));
                    z.w = fmaf(bq.x, s0.w, fmaf(bq.y, s1.w, fmaf(bq.z, s2.w, fmaf(bq.w, s3.w, z.w))));
                }
                *(float4*)&Z[i * 68 + n0] = z;
            }
            __syncthreads();

            // S -= K^T (ivd_j * Z) ; V += K^T Z   (ztq inline; iv16 straight
            // from invd_l: float4 at base-15,-11,-7,-3 (16-aligned), reversed)
            {
                const int n0 = (t & 15) * 4;
                const int mh = t >> 4;
                float iv16[16];
#pragma unroll
                for (int q4 = 0; q4 < 4; ++q4) {
                    const float4 v4 = *(const float4*)&invd_l[base - 15 + 4 * q4];
                    // invd_l[base-15+4q4 + w] corresponds to j = 15-4*q4-w
                    iv16[15 - 4 * q4]     = v4.x;
                    iv16[15 - 4 * q4 - 1] = v4.y;
                    iv16[15 - 4 * q4 - 2] = v4.z;
                    iv16[15 - 4 * q4 - 3] = v4.w;
                }
                float4 sacc[4], vacc[4];
#pragma unroll
                for (int p = 0; p < 4; ++p) {
                    sacc[p] = *(float4*)&S[(mh + 16 * p) * 68 + n0];
                    vacc[p] = *(float4*)&V[(mh + 16 * p) * 68 + n0];
                }
#pragma unroll
                for (int j = 0; j < 16; ++j) {
                    const float4 zq = *(const float4*)&Z[j * 68 + n0];
                    const float iv = iv16[j];
                    float4 ztq;
                    ztq.x = zq.x * iv; ztq.y = zq.y * iv;
                    ztq.z = zq.z * iv; ztq.w = zq.w * iv;
                    const float* kr = &hrows[(base - j) * 68];
                    const float k0 = kr[mh];
                    const float k1 = kr[mh + 16];
                    const float k2 = kr[mh + 32];
                    const float k3 = kr[mh + 48];
                    vacc[0].x = fmaf(k0, zq.x, vacc[0].x); vacc[0].y = fmaf(k0, zq.y, vacc[0].y);
                    vacc[0].z = fmaf(k0, zq.z, vacc[0].z); vacc[0].w = fmaf(k0, zq.w, vacc[0].w);
                    vacc[1].x = fmaf(k1, zq.x, vacc[1].x); vacc[1].y = fmaf(k1, zq.y, vacc[1].y);
                    vacc[1].z = fmaf(k1, zq.z, vacc[1].z); vacc[1].w = fmaf(k1, zq.w, vacc[1].w);
                    vacc[2].x = fmaf(k2, zq.x, vacc[2].x); vacc[2].y = fmaf(k2, zq.y, vacc[2].y);
                    vacc[2].z = fmaf(k2, zq.z, vacc[2].z); vacc[2].w = fmaf(k2, zq.w, vacc[2].w);
                    vacc[3].x = fmaf(k3, zq.x, vacc[3].x); vacc[3].y = fmaf(k3, zq.y, vacc[3].y);
                    vacc[3].z = fmaf(k3, zq.z, vacc[3].z); vacc[3].w = fmaf(k3, zq.w, vacc[3].w);
                    sacc[0].x = fmaf(-k0, ztq.x, sacc[0].x); sacc[0].y = fmaf(-k0, ztq.y, sacc[0].y);
                    sacc[0].z = fmaf(-k0, ztq.z, sacc[0].z); sacc[0].w = fmaf(-k0, ztq.w, sacc[0].w);
                    sacc[1].x = fmaf(-k1, ztq.x, sacc[1].x); sacc[1].y = fmaf(-k1, ztq.y, sacc[1].y);
                    sacc[1].z = fmaf(-k1, ztq.z, sacc[1].z); sacc[1].w = fmaf(-k1, ztq.w, sacc[1].w);
                    sacc[2].x = fmaf(-k2, ztq.x, sacc[2].x); sacc[2].y = fmaf(-k2, ztq.y, sacc[2].y);
                    sacc[2].z = fmaf(-k2, ztq.z, sacc[2].z); sacc[2].w = fmaf(-k2, ztq.w, sacc[2].w);
                    sacc[3].x = fmaf(-k3, ztq.x, sacc[3].x); sacc[3].y = fmaf(-k3, ztq.y, sacc[3].y);
                    sacc[3].z = fmaf(-k3, ztq.z, sacc[3].z); sacc[3].w = fmaf(-k3, ztq.w, sacc[3].w);
                }
#pragma unroll
                for (int p = 0; p < 4; ++p) {
                    *(float4*)&S[(mh + 16 * p) * 68 + n0] = sacc[p];
                    *(float4*)&V[(mh + 16 * p) * 68 + n0] = vacc[p];
                }
            }
        }
        __syncthreads();

        // writeback: pk[j*64+i] = pack(bf16(S[i][j]), bf16(V[i][j]))
        u32* pk = PK + ((size_t)(b * NSEG + s) << 12);
        for (int idx = t; idx < 4096; idx += 256) {
            const int j = idx >> 6, i = idx & 63;
            const u32 sb = ((u32)f2bf(S[i * 68 + j])) << 16;
            const u32 vb = (u32)f2bf(V[i * 68 + j]);
            pk[idx] = sb | vb;
        }
    }
}

// ---------------------------------------------------------------------------
// Kernel B: serial segment pass + output projection (unchanged from R11).
// 16 blocks x 256 threads (4 waves/batch), next-segment loads prefetched.
// ---------------------------------------------------------------------------
__global__ __launch_bounds__(256, 1) void final_kernel(
    const u16* __restrict__ q_ws, const u32* __restrict__ PK,
    const float* __restrict__ Wr, const float* __restrict__ br,
    const float* __restrict__ Wo, const float* __restrict__ bo,
    float* __restrict__ out)
{
    const int b    = blockIdx.x;
    const int t    = threadIdx.x;
    const int lane = t & 63;
    const int p    = t >> 6;         // wave id = j-slice

    __shared__ float psum[4][72];
    __shared__ float rl[64];
    __shared__ float cs[64], rs[64];

    rl[lane] = bf2f(q_ws[b * 64 + lane]);

    float ctxp = 0.f;
    u32 cur[16], nxt[16];
    {
        const u32* pk0 = PK + ((size_t)(b * NSEG + 0) << 12);
#pragma unroll
        for (int jj = 0; jj < 16; ++jj)
            cur[jj] = pk0[(p * 16 + jj) * 64 + lane];
    }
    __syncthreads();

    for (int s = 0; s < NSEG; ++s) {
        const int sn = (s + 1 < NSEG) ? s + 1 : s;
        const u32* pkn = PK + ((size_t)(b * NSEG + sn) << 12);
#pragma unroll
        for (int jj = 0; jj < 16; ++jj)
            nxt[jj] = pkn[(p * 16 + jj) * 64 + lane];

        float accr = 0.f;
#pragma unroll
        for (int jj = 0; jj < 16; ++jj) {
            const u32 pv = cur[jj];
            const float Sv = __uint_as_float(pv & 0xFFFF0000u);
            const float Vv = __uint_as_float(pv << 16);
            const float rj = rl[p * 16 + jj];
            accr = fmaf(Sv, rj, accr);
            ctxp = fmaf(Vv, rj, ctxp);
        }
        psum[p][lane] = accr;
        __syncthreads();
        const float rn = (psum[0][lane] + psum[1][lane]) + (psum[2][lane] + psum[3][lane]);
        __syncthreads();
        rl[lane] = rn;

#pragma unroll
        for (int jj = 0; jj < 16; ++jj) cur[jj] = nxt[jj];
    }

    psum[p][lane] = ctxp;
    __syncthreads();
    if (t < 64)
        cs[t] = (psum[0][t] + psum[1][t]) + (psum[2][t] + psum[3][t]);
    __syncthreads();

    float rv = (p == 0) ? br[lane] : 0.f;
#pragma unroll
    for (int i = 0; i < 16; ++i)
        rv = fmaf(cs[p * 16 + i], Wr[(p * 16 + i) * HDIM + lane], rv);
    psum[p][lane] = rv;
    __syncthreads();
    if (t < 64)
        rs[t] = (psum[0][t] + psum[1][t]) + (psum[2][t] + psum[3][t]);
    __syncthreads();

    float ov = (p == 0) ? bo[lane] : 0.f;
#pragma unroll
    for (int i = 0; i < 16; ++i)
        ov = fmaf(rs[p * 16 + i], Wo[(p * 16 + i) * HDIM + lane], ov);
    psum[p][lane] = ov;
    __syncthreads();
    if (t < 64)
        out[(size_t)b * HDIM + t] = (psum[0][t] + psum[1][t]) + (psum[2][t] + psum[3][t]);
}

// ---------------------------------------------------------------------------
extern "C" void kernel_launch(void* const* d_in, const int* in_sizes, int n_in,
                              void* d_out, int out_size, void* d_ws, size_t ws_size,
                              hipStream_t stream)
{
    const int*   seq   = (const int*)  d_in[0];
    const float* embed = (const float*)d_in[1];
    const float* W1    = (const float*)d_in[2];
    const float* b1    = (const float*)d_in[3];
    const float* W2    = (const float*)d_in[4];
    const float* b2    = (const float*)d_in[5];
    const float* gamma = (const float*)d_in[6];
    const float* beta  = (const float*)d_in[7];
    const float* Wr    = (const float*)d_in[8];
    const float* br    = (const float*)d_in[9];
    const float* Wo    = (const float*)d_in[10];
    const float* bo    = (const float*)d_in[11];

    u32* pk_ws = (u32*)d_ws;                                  // 4 MB
    u16* q_ws  = (u16*)(pk_ws + (size_t)BATCH * NSEG * 4096); // 2 KB
    float* outp = (float*)d_out;

    hipLaunchKernelGGL(fused_pc_kernel, dim3(BATCH * NSEG), dim3(256), 0, stream,
                       seq, embed, W1, b1, W2, b2, gamma, beta, pk_ws, q_ws);
    hipLaunchKernelGGL(final_kernel, dim3(BATCH), dim3(256), 0, stream,
                       q_ws, pk_ws, Wr, br, Wo, bo, outp);
}

// Round 15
// 139.326 us; speedup vs baseline: 1.1961x; 1.0118x over previous
//
#include <hip/hip_runtime.h>

// Problem constants
#define HDIM 64
#define LSEQ 2048
#define BATCH 16
#define LN_EPS 1e-5f
#define D_EPS 1e-6f
#define NSEG 16      // segments per batch
#define CPS 8        // chunks per segment (16 tokens each) -> 128 tokens/block

typedef unsigned short u16;
typedef unsigned int   u32;

__device__ __forceinline__ float bf2f(u16 v) {
    return __uint_as_float(((u32)v) << 16);
}
__device__ __forceinline__ u16 f2bf(float f) {   // round-to-nearest-even
    u32 u = __float_as_uint(f);
    return (u16)((u + 0x7FFFu + ((u >> 16) & 1u)) >> 16);
}

// ---------------- shared-memory overlay (bytes) ----------------
// Phase A scratch (dead after preprocess):
#define P_SW1   0        // f32[64*132]  33792
#define P_SW2   33792    // f32[128*68]  34816
#define P_ET    68608    // f32[64*68]   17408
#define P_HIDT  86016    // f32[128*68]  34816
#define P_RED1  120832   // f32[4*66]    1056
#define P_RED2  121888   // f32[4*66]    1056
#define P_SMU   122944   // f32[68]      272
#define P_SRSTD 123216   // f32[68]      272
// Persistent across phases A/B:
#define H_ROWS  123488   // f32[128*68]  34816  (bf16-rounded h, row-major)
#define H_INVD  158304   // f32[128]     512
#define SMEM_BYTES 158816
// Compose overlays phase-A scratch:
#define C_S     0        // f32[64*68]   17408
#define C_V     17408    // f32[64*68]   17408
#define C_BM    34816    // f32[16*68]   4352
#define C_Z     39168    // f32[16*68]   4352
#define C_GM    43520    // f32[16*17]   1088

// ---------------------------------------------------------------------------
// Kernel A: fused preprocess + segment composition (R14 structure; R15: the
// hidT stores in MLP1 and the eT read-modify-write in MLP2 are vectorized to
// float4 — 32 ds_write_b32 -> 8 ds_write_b128 and 16 b32 RMW -> 4 b128 RMW
// per thread per tile. Same addresses, same values: bit-identical numerics;
// removes the 8-way scalar-store bank conflicts.
// Block = (batch b, segment s) consumes tokens [1920-128s, 2047-128s].
// ---------------------------------------------------------------------------
__global__ __launch_bounds__(256, 1) void fused_pc_kernel(
    const int* __restrict__ seq, const float* __restrict__ embed,
    const float* __restrict__ W1, const float* __restrict__ b1,
    const float* __restrict__ W2, const float* __restrict__ b2,
    const float* __restrict__ gamma, const float* __restrict__ beta,
    u32* __restrict__ PK, u16* __restrict__ q_ws)
{
    __shared__ __align__(16) char smem[SMEM_BYTES];
    const int t = threadIdx.x;
    const int b = blockIdx.x >> 4;
    const int s = blockIdx.x & 15;
    const int tok0 = 1920 - 128 * s;          // first token of this block

    float* hrows  = (float*)(smem + H_ROWS);
    float* invd_l = (float*)(smem + H_INVD);

    // ======================= Phase A: preprocess ==========================
    {
        float* sW1   = (float*)(smem + P_SW1);
        float* sW2   = (float*)(smem + P_SW2);
        float* eT    = (float*)(smem + P_ET);
        float* hidT  = (float*)(smem + P_HIDT);
        float* red1  = (float*)(smem + P_RED1);
        float* red2  = (float*)(smem + P_RED2);
        float* smu   = (float*)(smem + P_SMU);
        float* srstd = (float*)(smem + P_SRSTD);

        // stage W1 (64x128, stride 132) and W2 (128x64, stride 68) once
        {
            const float4* s1 = (const float4*)W1;   // 2048 float4
#pragma unroll
            for (int q = 0; q < 8; ++q) {
                const int m = t + 256 * q;
                const int row = m >> 5, col = m & 31;
                *(float4*)&sW1[row * 132 + col * 4] = s1[m];
            }
            const float4* s2 = (const float4*)W2;   // 2048 float4
#pragma unroll
            for (int q = 0; q < 8; ++q) {
                const int m = t + 256 * q;
                const int row = m >> 4, col = m & 15;
                *(float4*)&sW2[row * 68 + col * 4] = s2[m];
            }
        }

        for (int it = 0; it < 2; ++it) {
            const int g0 = b * LSEQ + tok0 + 64 * it;   // global token base
            __syncthreads();   // W staging (it=0) / prior tile reads (it=1)

            // stage embeddings transposed: thread (tk = t>>2, p = t&3)
            {
                const int tk = t >> 2, p = t & 3;
                const int v = seq[g0 + tk];
                const float* er = embed + v * HDIM + 16 * p;
#pragma unroll
                for (int q = 0; q < 4; ++q) {
                    const float4 ev = *(const float4*)(er + 4 * q);
                    const int d = 16 * p + 4 * q;
                    eT[(d + 0) * 68 + tk] = ev.x;
                    eT[(d + 1) * 68 + tk] = ev.y;
                    eT[(d + 2) * 68 + tk] = ev.z;
                    eT[(d + 3) * 68 + tk] = ev.w;
                }
            }
            __syncthreads();

            const int r = t >> 4;   // token quad
            const int c = t & 15;   // out quad

            // MLP1: hid = relu(e W1 + b1); float4 stores (R15)
            {
                float acc0[4][4], acc1[4][4];
#pragma unroll
                for (int o = 0; o < 4; ++o) {
                    const float bA = b1[4 * c + o];
                    const float bB = b1[64 + 4 * c + o];
#pragma unroll
                    for (int j = 0; j < 4; ++j) { acc0[j][o] = bA; acc1[j][o] = bB; }
                }
                for (int k = 0; k < 64; ++k) {
                    const float4 ev = *(const float4*)&eT[k * 68 + 4 * r];
                    const float4 wa = *(const float4*)&sW1[k * 132 + 4 * c];
                    const float4 wb = *(const float4*)&sW1[k * 132 + 64 + 4 * c];
                    const float e4[4] = {ev.x, ev.y, ev.z, ev.w};
                    const float a4[4] = {wa.x, wa.y, wa.z, wa.w};
                    const float b4[4] = {wb.x, wb.y, wb.z, wb.w};
#pragma unroll
                    for (int j = 0; j < 4; ++j)
#pragma unroll
                        for (int o = 0; o < 4; ++o) {
                            acc0[j][o] = fmaf(e4[j], a4[o], acc0[j][o]);
                            acc1[j][o] = fmaf(e4[j], b4[o], acc1[j][o]);
                        }
                }
#pragma unroll
                for (int o = 0; o < 4; ++o) {
                    const float4 v0 = make_float4(fmaxf(acc0[0][o], 0.f), fmaxf(acc0[1][o], 0.f),
                                                  fmaxf(acc0[2][o], 0.f), fmaxf(acc0[3][o], 0.f));
                    *(float4*)&hidT[(4 * c + o) * 68 + 4 * r] = v0;
                    const float4 v1 = make_float4(fmaxf(acc1[0][o], 0.f), fmaxf(acc1[1][o], 0.f),
                                                  fmaxf(acc1[2][o], 0.f), fmaxf(acc1[3][o], 0.f));
                    *(float4*)&hidT[(64 + 4 * c + o) * 68 + 4 * r] = v1;
                }
            }
            __syncthreads();

            // MLP2: ff = hid W2 + b2; x = e + ff in place into eT (b128 RMW)
            {
                float acc[4][4];
#pragma unroll
                for (int o = 0; o < 4; ++o) {
                    const float bv = b2[4 * c + o];
#pragma unroll
                    for (int j = 0; j < 4; ++j) acc[j][o] = bv;
                }
                for (int k = 0; k < 128; ++k) {
                    const float4 hv = *(const float4*)&hidT[k * 68 + 4 * r];
                    const float4 wv = *(const float4*)&sW2[k * 68 + 4 * c];
                    const float h4[4] = {hv.x, hv.y, hv.z, hv.w};
                    const float w4[4] = {wv.x, wv.y, wv.z, wv.w};
#pragma unroll
                    for (int j = 0; j < 4; ++j)
#pragma unroll
                        for (int o = 0; o < 4; ++o)
                            acc[j][o] = fmaf(h4[j], w4[o], acc[j][o]);
                }
#pragma unroll
                for (int o = 0; o < 4; ++o) {
                    float4 ex = *(float4*)&eT[(4 * c + o) * 68 + 4 * r];
                    ex.x += acc[0][o];
                    ex.y += acc[1][o];
                    ex.z += acc[2][o];
                    ex.w += acc[3][o];
                    *(float4*)&eT[(4 * c + o) * 68 + 4 * r] = ex;
                }
            }
            __syncthreads();

            // LN stats
            {
                const int tk = t & 63, p = t >> 6;
                float sv = 0.f, q = 0.f;
#pragma unroll
                for (int i = 0; i < 16; ++i) {
                    const float x = eT[(16 * p + i) * 68 + tk];
                    sv += x;
                    q = fmaf(x, x, q);
                }
                red1[p * 66 + tk] = sv;
                red2[p * 66 + tk] = q;
            }
            __syncthreads();
            if (t < 64) {
                const float sv = ((red1[0 * 66 + t] + red1[1 * 66 + t]) + (red1[2 * 66 + t] + red1[3 * 66 + t]));
                const float qq = ((red2[0 * 66 + t] + red2[1 * 66 + t]) + (red2[2 * 66 + t] + red2[3 * 66 + t]));
                const float mu  = sv * (1.0f / 64.0f);
                const float var = qq * (1.0f / 64.0f) - mu * mu;
                smu[t]   = mu;
                srstd[t] = 1.0f / sqrtf(var + LN_EPS);
            }
            __syncthreads();

            // normalize, round bf16, store rounded f32 into hrows; hh over
            // ROUNDED values; block (b,0) token 2047 exports q (bf16)
            {
                const int tk = t >> 2, p = t & 3;
                const float mu = smu[tk], rstd = srstd[tk];
                const int lrow = 64 * it + tk;
                float hh = 0.f;
#pragma unroll
                for (int i2 = 0; i2 < 8; ++i2) {
                    const int d = 16 * p + 2 * i2;
                    const float x0 = eT[(d + 0) * 68 + tk];
                    const float x1 = eT[(d + 1) * 68 + tk];
                    const float o0 = (x0 - mu) * rstd * gamma[d + 0] + beta[d + 0];
                    const float o1 = (x1 - mu) * rstd * gamma[d + 1] + beta[d + 1];
                    const u16 r0 = f2bf(o0), r1 = f2bf(o1);
                    const float q0f = bf2f(r0), q1f = bf2f(r1);
                    hh = fmaf(q0f, q0f, hh);
                    hh = fmaf(q1f, q1f, hh);
                    hrows[lrow * 68 + d]     = q0f;
                    hrows[lrow * 68 + d + 1] = q1f;
                    if (s == 0 && lrow == 127) {   // token 2047: export q
                        q_ws[b * 64 + d]     = r0;
                        q_ws[b * 64 + d + 1] = r1;
                    }
                }
                red1[p * 66 + tk] = hh;
            }
            __syncthreads();
            if (t < 64) {
                const float hh = ((red1[0 * 66 + t] + red1[1 * 66 + t]) + (red1[2 * 66 + t] + red1[3 * 66 + t]));
                invd_l[64 * it + t] = 1.0f / (hh + D_EPS);
            }
        }
    }
    __syncthreads();

    // zero the sigma=0 padded key (row 127 = token 2047, only segment 0)
    if (s == 0 && t < 64) hrows[127 * 68 + t] = 0.f;

    // ======================= Phase B: compose =============================
    {
        float* S  = (float*)(smem + C_S);
        float* V  = (float*)(smem + C_V);
        float* Bm = (float*)(smem + C_BM);
        float* Z  = (float*)(smem + C_Z);
        float* Gm = (float*)(smem + C_GM);

        // init S = I, V = 0
        for (int idx = t; idx < 64 * 64; idx += 256) {
            const int m = idx >> 6, n = idx & 63;
            S[m * 68 + n] = (m == n) ? 1.0f : 0.0f;
            V[m * 68 + n] = 0.0f;
        }

        for (int cc = 0; cc < CPS; ++cc) {
            const int base = 127 - 16 * cc;   // hrows row of solve-slot j is base-j
            __syncthreads();   // init / previous chunk reads done

            // Gram: Gm[i][j] = (k_i . k_j) * invd[base-j], i > j
            {
                const int i = t >> 4, j = t & 15;
                if (i > j) {
                    const float* ra = &hrows[(base - i) * 68];
                    const float* rb = &hrows[(base - j) * 68];
                    float acc = 0.f;
#pragma unroll
                    for (int m = 0; m < 64; m += 4) {
                        const float4 a  = *(const float4*)&ra[m];
                        const float4 bb = *(const float4*)&rb[m];
                        acc += a.x * bb.x + a.y * bb.y + a.z * bb.z + a.w * bb.w;
                    }
                    Gm[i * 17 + j] = acc * invd_l[base - j];
                }
            }
            __syncthreads();

            // B: forward substitution L B = K (wave 0)
            if (t < 64) {
                const int n = t;
                float Breg[16];
#pragma unroll
                for (int i = 0; i < 16; ++i) {
                    float acc = hrows[(base - i) * 68 + n];
#pragma unroll
                    for (int j = 0; j < 16; ++j)
                        if (j < i) acc = fmaf(-Gm[i * 17 + j], Breg[j], acc);
                    Breg[i] = acc;
                    Bm[i * 68 + n] = acc;
                }
            }
            __syncthreads();

            // Z = B S
            {
                const int i  = t & 15;
                const int n0 = (t >> 4) * 4;
                float4 z = make_float4(0.f, 0.f, 0.f, 0.f);
#pragma unroll
                for (int mq = 0; mq < 16; ++mq) {
                    const float4 bq = *(const float4*)&Bm[i * 68 + mq * 4];
                    const float4 s0 = *(const float4*)&S[(mq * 4 + 0) * 68 + n0];
                    const float4 s1 = *(const float4*)&S[(mq * 4 + 1) * 68 + n0];
                    const float4 s2 = *(const float4*)&S[(mq * 4 + 2) * 68 + n0];
                    const float4 s3 = *(const float4*)&S[(mq * 4 + 3) * 68 + n0];
                    z.x = fmaf(bq.x, s0.x, fmaf(bq.y, s1.x, fmaf(bq.z, s2.x, fmaf(bq.w, s3.x, z.x))));
                    z.y = fmaf(bq.x, s0.y, fmaf(bq.y, s1.y, fmaf(bq.z, s2.y, fmaf(bq.w, s3.y, z.y))));
                    z.z = fmaf(bq.x, s0.z, fmaf(bq.y, s1.z, fmaf(bq.z, s2.z, fmaf(bq.w, s3.z, z.z))));
                    z.w = fmaf(bq.x, s0.w, fmaf(bq.y, s1.w, fmaf(bq.z, s2.w, fmaf(bq.w, s3.w, z.w))));
                }
                *(float4*)&Z[i * 68 + n0] = z;
            }
            __syncthreads();

            // S -= K^T (ivd_j * Z) ; V += K^T Z   (ztq inline; iv16 straight
            // from invd_l: float4 at base-15,-11,-7,-3 (16-aligned), reversed)
            {
                const int n0 = (t & 15) * 4;
                const int mh = t >> 4;
                float iv16[16];
#pragma unroll
                for (int q4 = 0; q4 < 4; ++q4) {
                    const float4 v4 = *(const float4*)&invd_l[base - 15 + 4 * q4];
                    iv16[15 - 4 * q4]     = v4.x;
                    iv16[15 - 4 * q4 - 1] = v4.y;
                    iv16[15 - 4 * q4 - 2] = v4.z;
                    iv16[15 - 4 * q4 - 3] = v4.w;
                }
                float4 sacc[4], vacc[4];
#pragma unroll
                for (int p = 0; p < 4; ++p) {
                    sacc[p] = *(float4*)&S[(mh + 16 * p) * 68 + n0];
                    vacc[p] = *(float4*)&V[(mh + 16 * p) * 68 + n0];
                }
#pragma unroll
                for (int j = 0; j < 16; ++j) {
                    const float4 zq = *(const float4*)&Z[j * 68 + n0];
                    const float iv = iv16[j];
                    float4 ztq;
                    ztq.x = zq.x * iv; ztq.y = zq.y * iv;
                    ztq.z = zq.z * iv; ztq.w = zq.w * iv;
                    const float* kr = &hrows[(base - j) * 68];
                    const float k0 = kr[mh];
                    const float k1 = kr[mh + 16];
                    const float k2 = kr[mh + 32];
                    const float k3 = kr[mh + 48];
                    vacc[0].x = fmaf(k0, zq.x, vacc[0].x); vacc[0].y = fmaf(k0, zq.y, vacc[0].y);
                    vacc[0].z = fmaf(k0, zq.z, vacc[0].z); vacc[0].w = fmaf(k0, zq.w, vacc[0].w);
                    vacc[1].x = fmaf(k1, zq.x, vacc[1].x); vacc[1].y = fmaf(k1, zq.y, vacc[1].y);
                    vacc[1].z = fmaf(k1, zq.z, vacc[1].z); vacc[1].w = fmaf(k1, zq.w, vacc[1].w);
                    vacc[2].x = fmaf(k2, zq.x, vacc[2].x); vacc[2].y = fmaf(k2, zq.y, vacc[2].y);
                    vacc[2].z = fmaf(k2, zq.z, vacc[2].z); vacc[2].w = fmaf(k2, zq.w, vacc[2].w);
                    vacc[3].x = fmaf(k3, zq.x, vacc[3].x); vacc[3].y = fmaf(k3, zq.y, vacc[3].y);
                    vacc[3].z = fmaf(k3, zq.z, vacc[3].z); vacc[3].w = fmaf(k3, zq.w, vacc[3].w);
                    sacc[0].x = fmaf(-k0, ztq.x, sacc[0].x); sacc[0].y = fmaf(-k0, ztq.y, sacc[0].y);
                    sacc[0].z = fmaf(-k0, ztq.z, sacc[0].z); sacc[0].w = fmaf(-k0, ztq.w, sacc[0].w);
                    sacc[1].x = fmaf(-k1, ztq.x, sacc[1].x); sacc[1].y = fmaf(-k1, ztq.y, sacc[1].y);
                    sacc[1].z = fmaf(-k1, ztq.z, sacc[1].z); sacc[1].w = fmaf(-k1, ztq.w, sacc[1].w);
                    sacc[2].x = fmaf(-k2, ztq.x, sacc[2].x); sacc[2].y = fmaf(-k2, ztq.y, sacc[2].y);
                    sacc[2].z = fmaf(-k2, ztq.z, sacc[2].z); sacc[2].w = fmaf(-k2, ztq.w, sacc[2].w);
                    sacc[3].x = fmaf(-k3, ztq.x, sacc[3].x); sacc[3].y = fmaf(-k3, ztq.y, sacc[3].y);
                    sacc[3].z = fmaf(-k3, ztq.z, sacc[3].z); sacc[3].w = fmaf(-k3, ztq.w, sacc[3].w);
                }
#pragma unroll
                for (int p = 0; p < 4; ++p) {
                    *(float4*)&S[(mh + 16 * p) * 68 + n0] = sacc[p];
                    *(float4*)&V[(mh + 16 * p) * 68 + n0] = vacc[p];
                }
            }
        }
        __syncthreads();

        // writeback: pk[j*64+i] = pack(bf16(S[i][j]), bf16(V[i][j]))
        u32* pk = PK + ((size_t)(b * NSEG + s) << 12);
        for (int idx = t; idx < 4096; idx += 256) {
            const int j = idx >> 6, i = idx & 63;
            const u32 sb = ((u32)f2bf(S[i * 68 + j])) << 16;
            const u32 vb = (u32)f2bf(V[i * 68 + j]);
            pk[idx] = sb | vb;
        }
    }
}

// ---------------------------------------------------------------------------
// Kernel B: serial segment pass + output projection (unchanged from R11/R14).
// 16 blocks x 256 threads (4 waves/batch), next-segment loads prefetched.
// ---------------------------------------------------------------------------
__global__ __launch_bounds__(256, 1) void final_kernel(
    const u16* __restrict__ q_ws, const u32* __restrict__ PK,
    const float* __restrict__ Wr, const float* __restrict__ br,
    const float* __restrict__ Wo, const float* __restrict__ bo,
    float* __restrict__ out)
{
    const int b    = blockIdx.x;
    const int t    = threadIdx.x;
    const int lane = t & 63;
    const int p    = t >> 6;         // wave id = j-slice

    __shared__ float psum[4][72];
    __shared__ float rl[64];
    __shared__ float cs[64], rs[64];

    rl[lane] = bf2f(q_ws[b * 64 + lane]);

    float ctxp = 0.f;
    u32 cur[16], nxt[16];
    {
        const u32* pk0 = PK + ((size_t)(b * NSEG + 0) << 12);
#pragma unroll
        for (int jj = 0; jj < 16; ++jj)
            cur[jj] = pk0[(p * 16 + jj) * 64 + lane];
    }
    __syncthreads();

    for (int s = 0; s < NSEG; ++s) {
        const int sn = (s + 1 < NSEG) ? s + 1 : s;
        const u32* pkn = PK + ((size_t)(b * NSEG + sn) << 12);
#pragma unroll
        for (int jj = 0; jj < 16; ++jj)
            nxt[jj] = pkn[(p * 16 + jj) * 64 + lane];

        float accr = 0.f;
#pragma unroll
        for (int jj = 0; jj < 16; ++jj) {
            const u32 pv = cur[jj];
            const float Sv = __uint_as_float(pv & 0xFFFF0000u);
            const float Vv = __uint_as_float(pv << 16);
            const float rj = rl[p * 16 + jj];
            accr = fmaf(Sv, rj, accr);
            ctxp = fmaf(Vv, rj, ctxp);
        }
        psum[p][lane] = accr;
        __syncthreads();
        const float rn = (psum[0][lane] + psum[1][lane]) + (psum[2][lane] + psum[3][lane]);
        __syncthreads();
        rl[lane] = rn;

#pragma unroll
        for (int jj = 0; jj < 16; ++jj) cur[jj] = nxt[jj];
    }

    psum[p][lane] = ctxp;
    __syncthreads();
    if (t < 64)
        cs[t] = (psum[0][t] + psum[1][t]) + (psum[2][t] + psum[3][t]);
    __syncthreads();

    float rv = (p == 0) ? br[lane] : 0.f;
#pragma unroll
    for (int i = 0; i < 16; ++i)
        rv = fmaf(cs[p * 16 + i], Wr[(p * 16 + i) * HDIM + lane], rv);
    psum[p][lane] = rv;
    __syncthreads();
    if (t < 64)
        rs[t] = (psum[0][t] + psum[1][t]) + (psum[2][t] + psum[3][t]);
    __syncthreads();

    float ov = (p == 0) ? bo[lane] : 0.f;
#pragma unroll
    for (int i = 0; i < 16; ++i)
        ov = fmaf(rs[p * 16 + i], Wo[(p * 16 + i) * HDIM + lane], ov);
    psum[p][lane] = ov;
    __syncthreads();
    if (t < 64)
        out[(size_t)b * HDIM + t] = (psum[0][t] + psum[1][t]) + (psum[2][t] + psum[3][t]);
}

// ---------------------------------------------------------------------------
extern "C" void kernel_launch(void* const* d_in, const int* in_sizes, int n_in,
                              void* d_out, int out_size, void* d_ws, size_t ws_size,
                              hipStream_t stream)
{
    const int*   seq   = (const int*)  d_in[0];
    const float* embed = (const float*)d_in[1];
    const float* W1    = (const float*)d_in[2];
    const float* b1    = (const float*)d_in[3];
    const float* W2    = (const float*)d_in[4];
    const float* b2    = (const float*)d_in[5];
    const float* gamma = (const float*)d_in[6];
    const float* beta  = (const float*)d_in[7];
    const float* Wr    = (const float*)d_in[8];
    const float* br    = (const float*)d_in[9];
    const float* Wo    = (const float*)d_in[10];
    const float* bo    = (const float*)d_in[11];

    u32* pk_ws = (u32*)d_ws;                                  // 4 MB
    u16* q_ws  = (u16*)(pk_ws + (size_t)BATCH * NSEG * 4096); // 2 KB
    float* outp = (float*)d_out;

    hipLaunchKernelGGL(fused_pc_kernel, dim3(BATCH * NSEG), dim3(256), 0, stream,
                       seq, embed, W1, b1, W2, b2, gamma, beta, pk_ws, q_ws);
    hipLaunchKernelGGL(final_kernel, dim3(BATCH), dim3(256), 0, stream,
                       q_ws, pk_ws, Wr, br, Wo, bo, outp);
}

// Round 16
// 139.105 us; speedup vs baseline: 1.1980x; 1.0016x over previous
//
#include <hip/hip_runtime.h>

// Problem constants
#define HDIM 64
#define LSEQ 2048
#define BATCH 16
#define LN_EPS 1e-5f
#define D_EPS 1e-6f
#define NSEG 32      // segments per batch (R16: 64 tokens per block)
#define CPS 4        // chunks per segment (16 tokens each)

typedef unsigned short u16;
typedef unsigned int   u32;

__device__ __forceinline__ float bf2f(u16 v) {
    return __uint_as_float(((u32)v) << 16);
}
__device__ __forceinline__ u16 f2bf(float f) {   // round-to-nearest-even
    u32 u = __float_as_uint(f);
    return (u16)((u + 0x7FFFu + ((u >> 16) & 1u)) >> 16);
}

// ---------------- shared-memory overlay (bytes), total 80736 ----------------
// 2 blocks/CU: 2 x 80736 = 161472 <= 163840.
// Phase A scratch (dead after preprocess):
#define A_SW1   0        // bf16[64*132]  16896
#define A_SW2   16896    // bf16[128*68]  17408
#define A_ET    34304    // f32 [64*68]   17408
#define A_HIDT  51712    // bf16[128*68]  17408
#define A_RED1  69120    // f32 [4*66]    1056
#define A_RED2  70176    // f32 [4*66]    1056
#define A_SMU   71232    // f32 [66]      272
#define A_SRSTD 71504    // f32 [66]      272
// Persistent across phases A/B:
#define H_ROWS  71776    // bf16[64*68]   8704   (bf16 h — lossless, h is bf16-rounded)
#define H_INVD  80480    // f32 [64]      256
#define SMEM_BYTES 80736
// Compose overlays phase-A scratch (all < 71776):
#define C_S     0        // f32[64*68]   17408
#define C_V     17408    // f32[64*68]   17408
#define C_BM    34816    // f32[16*68]   4352
#define C_Z     39168    // f32[16*68]   4352
#define C_GM    43520    // f32[16*17]   1088

// ---------------------------------------------------------------------------
// Kernel A: fused preprocess + segment composition. R16: 512 blocks
// (batch b, segment s in 0..31), 64 tokens/block, 80.7 KB LDS -> 2 blocks/CU
// co-resident (independent blocks overlap each other's LDS/barrier stalls).
// W1/W2/hidT stored bf16 (numerics: extra bf16 rounding on weights+hidden);
// hrows bf16 (lossless — h already bf16-rounded); eT/S/V/Z/B f32.
// Block covers solve slots [64s, 64s+64) = tokens [1984-64s .. 2047-64s].
// ---------------------------------------------------------------------------
__global__ __launch_bounds__(256, 2) void fused_pc_kernel(
    const int* __restrict__ seq, const float* __restrict__ embed,
    const float* __restrict__ W1, const float* __restrict__ b1,
    const float* __restrict__ W2, const float* __restrict__ b2,
    const float* __restrict__ gamma, const float* __restrict__ beta,
    u32* __restrict__ PK, u16* __restrict__ q_ws)
{
    __shared__ __align__(16) char smem[SMEM_BYTES];
    const int t = threadIdx.x;
    const int b = blockIdx.x >> 5;
    const int s = blockIdx.x & 31;
    const int tok0 = 1984 - 64 * s;           // first token of this block

    u16*   hrows  = (u16*)(smem + H_ROWS);
    float* invd_l = (float*)(smem + H_INVD);

    // ======================= Phase A: preprocess ==========================
    {
        u16*   sW1   = (u16*)(smem + A_SW1);
        u16*   sW2   = (u16*)(smem + A_SW2);
        float* eT    = (float*)(smem + A_ET);
        u16*   hidT  = (u16*)(smem + A_HIDT);
        float* red1  = (float*)(smem + A_RED1);
        float* red2  = (float*)(smem + A_RED2);
        float* smu   = (float*)(smem + A_SMU);
        float* srstd = (float*)(smem + A_SRSTD);

        // stage W1 (64x128) and W2 (128x64) as bf16
        {
            const float4* s1 = (const float4*)W1;   // 2048 float4
#pragma unroll
            for (int q = 0; q < 8; ++q) {
                const int m = t + 256 * q;
                const int row = m >> 5, col = m & 31;
                const float4 v = s1[m];
                ushort4 w;
                w.x = f2bf(v.x); w.y = f2bf(v.y); w.z = f2bf(v.z); w.w = f2bf(v.w);
                *(ushort4*)&sW1[row * 132 + col * 4] = w;
            }
            const float4* s2 = (const float4*)W2;   // 2048 float4
#pragma unroll
            for (int q = 0; q < 8; ++q) {
                const int m = t + 256 * q;
                const int row = m >> 4, col = m & 15;
                const float4 v = s2[m];
                ushort4 w;
                w.x = f2bf(v.x); w.y = f2bf(v.y); w.z = f2bf(v.z); w.w = f2bf(v.w);
                *(ushort4*)&sW2[row * 68 + col * 4] = w;
            }
        }
        // stage embeddings transposed: thread (tk = t>>2, p = t&3)
        {
            const int tk = t >> 2, p = t & 3;
            const int v = seq[b * LSEQ + tok0 + tk];
            const float* er = embed + v * HDIM + 16 * p;
#pragma unroll
            for (int q = 0; q < 4; ++q) {
                const float4 ev = *(const float4*)(er + 4 * q);
                const int d = 16 * p + 4 * q;
                eT[(d + 0) * 68 + tk] = ev.x;
                eT[(d + 1) * 68 + tk] = ev.y;
                eT[(d + 2) * 68 + tk] = ev.z;
                eT[(d + 3) * 68 + tk] = ev.w;
            }
        }
        __syncthreads();

        const int r = t >> 4;   // token quad
        const int c = t & 15;   // out quad

        // MLP1: hid = relu(e W1 + b1), bf16 weights, bf16 hid store
        {
            float acc0[4][4], acc1[4][4];
#pragma unroll
            for (int o = 0; o < 4; ++o) {
                const float bA = b1[4 * c + o];
                const float bB = b1[64 + 4 * c + o];
#pragma unroll
                for (int j = 0; j < 4; ++j) { acc0[j][o] = bA; acc1[j][o] = bB; }
            }
            for (int k = 0; k < 64; ++k) {
                const float4  ev = *(const float4*)&eT[k * 68 + 4 * r];
                const ushort4 wa = *(const ushort4*)&sW1[k * 132 + 4 * c];
                const ushort4 wb = *(const ushort4*)&sW1[k * 132 + 64 + 4 * c];
                const float e4[4] = {ev.x, ev.y, ev.z, ev.w};
                const float a4[4] = {bf2f(wa.x), bf2f(wa.y), bf2f(wa.z), bf2f(wa.w)};
                const float b4[4] = {bf2f(wb.x), bf2f(wb.y), bf2f(wb.z), bf2f(wb.w)};
#pragma unroll
                for (int j = 0; j < 4; ++j)
#pragma unroll
                    for (int o = 0; o < 4; ++o) {
                        acc0[j][o] = fmaf(e4[j], a4[o], acc0[j][o]);
                        acc1[j][o] = fmaf(e4[j], b4[o], acc1[j][o]);
                    }
            }
#pragma unroll
            for (int o = 0; o < 4; ++o) {
                ushort4 v0, v1;
                v0.x = f2bf(fmaxf(acc0[0][o], 0.f)); v0.y = f2bf(fmaxf(acc0[1][o], 0.f));
                v0.z = f2bf(fmaxf(acc0[2][o], 0.f)); v0.w = f2bf(fmaxf(acc0[3][o], 0.f));
                *(ushort4*)&hidT[(4 * c + o) * 68 + 4 * r] = v0;
                v1.x = f2bf(fmaxf(acc1[0][o], 0.f)); v1.y = f2bf(fmaxf(acc1[1][o], 0.f));
                v1.z = f2bf(fmaxf(acc1[2][o], 0.f)); v1.w = f2bf(fmaxf(acc1[3][o], 0.f));
                *(ushort4*)&hidT[(64 + 4 * c + o) * 68 + 4 * r] = v1;
            }
        }
        __syncthreads();

        // MLP2: ff = hid W2 + b2; x = e + ff in place into eT
        {
            float acc[4][4];
#pragma unroll
            for (int o = 0; o < 4; ++o) {
                const float bv = b2[4 * c + o];
#pragma unroll
                for (int j = 0; j < 4; ++j) acc[j][o] = bv;
            }
            for (int k = 0; k < 128; ++k) {
                const ushort4 hv = *(const ushort4*)&hidT[k * 68 + 4 * r];
                const ushort4 wv = *(const ushort4*)&sW2[k * 68 + 4 * c];
                const float h4[4] = {bf2f(hv.x), bf2f(hv.y), bf2f(hv.z), bf2f(hv.w)};
                const float w4[4] = {bf2f(wv.x), bf2f(wv.y), bf2f(wv.z), bf2f(wv.w)};
#pragma unroll
                for (int j = 0; j < 4; ++j)
#pragma unroll
                    for (int o = 0; o < 4; ++o)
                        acc[j][o] = fmaf(h4[j], w4[o], acc[j][o]);
            }
#pragma unroll
            for (int o = 0; o < 4; ++o) {
                float4 ex = *(float4*)&eT[(4 * c + o) * 68 + 4 * r];
                ex.x += acc[0][o];
                ex.y += acc[1][o];
                ex.z += acc[2][o];
                ex.w += acc[3][o];
                *(float4*)&eT[(4 * c + o) * 68 + 4 * r] = ex;
            }
        }
        __syncthreads();

        // LN stats
        {
            const int tk = t & 63, p = t >> 6;
            float sv = 0.f, q = 0.f;
#pragma unroll
            for (int i = 0; i < 16; ++i) {
                const float x = eT[(16 * p + i) * 68 + tk];
                sv += x;
                q = fmaf(x, x, q);
            }
            red1[p * 66 + tk] = sv;
            red2[p * 66 + tk] = q;
        }
        __syncthreads();
        if (t < 64) {
            const float sv = ((red1[0 * 66 + t] + red1[1 * 66 + t]) + (red1[2 * 66 + t] + red1[3 * 66 + t]));
            const float qq = ((red2[0 * 66 + t] + red2[1 * 66 + t]) + (red2[2 * 66 + t] + red2[3 * 66 + t]));
            const float mu  = sv * (1.0f / 64.0f);
            const float var = qq * (1.0f / 64.0f) - mu * mu;
            smu[t]   = mu;
            srstd[t] = 1.0f / sqrtf(var + LN_EPS);
        }
        __syncthreads();

        // normalize, round bf16, store bf16 into hrows; hh over ROUNDED
        // values; block (b, s=0) local row 63 = token 2047 exports q
        {
            const int tk = t >> 2, p = t & 3;
            const float mu = smu[tk], rstd = srstd[tk];
            float hh = 0.f;
#pragma unroll
            for (int i2 = 0; i2 < 8; ++i2) {
                const int d = 16 * p + 2 * i2;
                const float x0 = eT[(d + 0) * 68 + tk];
                const float x1 = eT[(d + 1) * 68 + tk];
                const float o0 = (x0 - mu) * rstd * gamma[d + 0] + beta[d + 0];
                const float o1 = (x1 - mu) * rstd * gamma[d + 1] + beta[d + 1];
                const u16 r0 = f2bf(o0), r1 = f2bf(o1);
                const float q0f = bf2f(r0), q1f = bf2f(r1);
                hh = fmaf(q0f, q0f, hh);
                hh = fmaf(q1f, q1f, hh);
                *(u32*)&hrows[tk * 68 + d] = (u32)r0 | ((u32)r1 << 16);
                if (s == 0 && tk == 63) {   // token 2047: export q
                    q_ws[b * 64 + d]     = r0;
                    q_ws[b * 64 + d + 1] = r1;
                }
            }
            red1[p * 66 + tk] = hh;
        }
        __syncthreads();
        if (t < 64) {
            const float hh = ((red1[0 * 66 + t] + red1[1 * 66 + t]) + (red1[2 * 66 + t] + red1[3 * 66 + t]));
            invd_l[t] = 1.0f / (hh + D_EPS);
        }
    }
    __syncthreads();

    // zero the sigma=0 padded key (local row 63 = token 2047, only segment 0)
    if (s == 0 && t < 64) hrows[63 * 68 + t] = 0;

    // ======================= Phase B: compose =============================
    {
        float* S  = (float*)(smem + C_S);
        float* V  = (float*)(smem + C_V);
        float* Bm = (float*)(smem + C_BM);
        float* Z  = (float*)(smem + C_Z);
        float* Gm = (float*)(smem + C_GM);

        // init S = I, V = 0
        for (int idx = t; idx < 64 * 64; idx += 256) {
            const int m = idx >> 6, n = idx & 63;
            S[m * 68 + n] = (m == n) ? 1.0f : 0.0f;
            V[m * 68 + n] = 0.0f;
        }

        for (int cc = 0; cc < CPS; ++cc) {
            const int base = 63 - 16 * cc;   // hrows row of solve-slot j is base-j
            __syncthreads();   // init / previous chunk reads done

            // Gram: Gm[i][j] = (k_i . k_j) * invd[base-j], i > j
            {
                const int i = t >> 4, j = t & 15;
                if (i > j) {
                    const u16* ra = &hrows[(base - i) * 68];
                    const u16* rb = &hrows[(base - j) * 68];
                    float acc = 0.f;
#pragma unroll
                    for (int m = 0; m < 64; m += 4) {
                        const ushort4 a4 = *(const ushort4*)&ra[m];
                        const ushort4 b4 = *(const ushort4*)&rb[m];
                        acc += bf2f(a4.x) * bf2f(b4.x) + bf2f(a4.y) * bf2f(b4.y)
                             + bf2f(a4.z) * bf2f(b4.z) + bf2f(a4.w) * bf2f(b4.w);
                    }
                    Gm[i * 17 + j] = acc * invd_l[base - j];
                }
            }
            __syncthreads();

            // B: forward substitution L B = K (wave 0)
            if (t < 64) {
                const int n = t;
                float Breg[16];
#pragma unroll
                for (int i = 0; i < 16; ++i) {
                    float acc = bf2f(hrows[(base - i) * 68 + n]);
#pragma unroll
                    for (int j = 0; j < 16; ++j)
                        if (j < i) acc = fmaf(-Gm[i * 17 + j], Breg[j], acc);
                    Breg[i] = acc;
                    Bm[i * 68 + n] = acc;
                }
            }
            __syncthreads();

            // Z = B S
            {
                const int i  = t & 15;
                const int n0 = (t >> 4) * 4;
                float4 z = make_float4(0.f, 0.f, 0.f, 0.f);
#pragma unroll
                for (int mq = 0; mq < 16; ++mq) {
                    const float4 bq = *(const float4*)&Bm[i * 68 + mq * 4];
                    const float4 s0 = *(const float4*)&S[(mq * 4 + 0) * 68 + n0];
                    const float4 s1 = *(const float4*)&S[(mq * 4 + 1) * 68 + n0];
                    const float4 s2 = *(const float4*)&S[(mq * 4 + 2) * 68 + n0];
                    const float4 s3 = *(const float4*)&S[(mq * 4 + 3) * 68 + n0];
                    z.x = fmaf(bq.x, s0.x, fmaf(bq.y, s1.x, fmaf(bq.z, s2.x, fmaf(bq.w, s3.x, z.x))));
                    z.y = fmaf(bq.x, s0.y, fmaf(bq.y, s1.y, fmaf(bq.z, s2.y, fmaf(bq.w, s3.y, z.y))));
                    z.z = fmaf(bq.x, s0.z, fmaf(bq.y, s1.z, fmaf(bq.z, s2.z, fmaf(bq.w, s3.z, z.z))));
                    z.w = fmaf(bq.x, s0.w, fmaf(bq.y, s1.w, fmaf(bq.z, s2.w, fmaf(bq.w, s3.w, z.w))));
                }
                *(float4*)&Z[i * 68 + n0] = z;
            }
            __syncthreads();

            // S -= K^T (ivd_j * Z) ; V += K^T Z   (ztq inline; iv16 from
            // invd_l float4 at base-15..base (16-aligned), reversed)
            {
                const int n0 = (t & 15) * 4;
                const int mh = t >> 4;
                float iv16[16];
#pragma unroll
                for (int q4 = 0; q4 < 4; ++q4) {
                    const float4 v4 = *(const float4*)&invd_l[base - 15 + 4 * q4];
                    iv16[15 - 4 * q4]     = v4.x;
                    iv16[15 - 4 * q4 - 1] = v4.y;
                    iv16[15 - 4 * q4 - 2] = v4.z;
                    iv16[15 - 4 * q4 - 3] = v4.w;
                }
                float4 sacc[4], vacc[4];
#pragma unroll
                for (int p = 0; p < 4; ++p) {
                    sacc[p] = *(float4*)&S[(mh + 16 * p) * 68 + n0];
                    vacc[p] = *(float4*)&V[(mh + 16 * p) * 68 + n0];
                }
#pragma unroll
                for (int j = 0; j < 16; ++j) {
                    const float4 zq = *(const float4*)&Z[j * 68 + n0];
                    const float iv = iv16[j];
                    float4 ztq;
                    ztq.x = zq.x * iv; ztq.y = zq.y * iv;
                    ztq.z = zq.z * iv; ztq.w = zq.w * iv;
                    const u16* kr = &hrows[(base - j) * 68];
                    const float k0 = bf2f(kr[mh]);
                    const float k1 = bf2f(kr[mh + 16]);
                    const float k2 = bf2f(kr[mh + 32]);
                    const float k3 = bf2f(kr[mh + 48]);
                    vacc[0].x = fmaf(k0, zq.x, vacc[0].x); vacc[0].y = fmaf(k0, zq.y, vacc[0].y);
                    vacc[0].z = fmaf(k0, zq.z, vacc[0].z); vacc[0].w = fmaf(k0, zq.w, vacc[0].w);
                    vacc[1].x = fmaf(k1, zq.x, vacc[1].x); vacc[1].y = fmaf(k1, zq.y, vacc[1].y);
                    vacc[1].z = fmaf(k1, zq.z, vacc[1].z); vacc[1].w = fmaf(k1, zq.w, vacc[1].w);
                    vacc[2].x = fmaf(k2, zq.x, vacc[2].x); vacc[2].y = fmaf(k2, zq.y, vacc[2].y);
                    vacc[2].z = fmaf(k2, zq.z, vacc[2].z); vacc[2].w = fmaf(k2, zq.w, vacc[2].w);
                    vacc[3].x = fmaf(k3, zq.x, vacc[3].x); vacc[3].y = fmaf(k3, zq.y, vacc[3].y);
                    vacc[3].z = fmaf(k3, zq.z, vacc[3].z); vacc[3].w = fmaf(k3, zq.w, vacc[3].w);
                    sacc[0].x = fmaf(-k0, ztq.x, sacc[0].x); sacc[0].y = fmaf(-k0, ztq.y, sacc[0].y);
                    sacc[0].z = fmaf(-k0, ztq.z, sacc[0].z); sacc[0].w = fmaf(-k0, ztq.w, sacc[0].w);
                    sacc[1].x = fmaf(-k1, ztq.x, sacc[1].x); sacc[1].y = fmaf(-k1, ztq.y, sacc[1].y);
                    sacc[1].z = fmaf(-k1, ztq.z, sacc[1].z); sacc[1].w = fmaf(-k1, ztq.w, sacc[1].w);
                    sacc[2].x = fmaf(-k2, ztq.x, sacc[2].x); sacc[2].y = fmaf(-k2, ztq.y, sacc[2].y);
                    sacc[2].z = fmaf(-k2, ztq.z, sacc[2].z); sacc[2].w = fmaf(-k2, ztq.w, sacc[2].w);
                    sacc[3].x = fmaf(-k3, ztq.x, sacc[3].x); sacc[3].y = fmaf(-k3, ztq.y, sacc[3].y);
                    sacc[3].z = fmaf(-k3, ztq.z, sacc[3].z); sacc[3].w = fmaf(-k3, ztq.w, sacc[3].w);
                }
#pragma unroll
                for (int p = 0; p < 4; ++p) {
                    *(float4*)&S[(mh + 16 * p) * 68 + n0] = sacc[p];
                    *(float4*)&V[(mh + 16 * p) * 68 + n0] = vacc[p];
                }
            }
        }
        __syncthreads();

        // writeback: pk[j*64+i] = pack(bf16(S[i][j]), bf16(V[i][j]))
        u32* pk = PK + ((size_t)(b * NSEG + s) << 12);
        for (int idx = t; idx < 4096; idx += 256) {
            const int j = idx >> 6, i = idx & 63;
            const u32 sb = ((u32)f2bf(S[i * 68 + j])) << 16;
            const u32 vb = (u32)f2bf(V[i * 68 + j]);
            pk[idx] = sb | vb;
        }
    }
}

// ---------------------------------------------------------------------------
// Kernel B: serial segment pass + output projection (R11 structure, NSEG=32).
// 16 blocks x 256 threads (4 waves/batch), next-segment loads prefetched.
// ---------------------------------------------------------------------------
__global__ __launch_bounds__(256, 1) void final_kernel(
    const u16* __restrict__ q_ws, const u32* __restrict__ PK,
    const float* __restrict__ Wr, const float* __restrict__ br,
    const float* __restrict__ Wo, const float* __restrict__ bo,
    float* __restrict__ out)
{
    const int b    = blockIdx.x;
    const int t    = threadIdx.x;
    const int lane = t & 63;
    const int p    = t >> 6;         // wave id = j-slice

    __shared__ float psum[4][72];
    __shared__ float rl[64];
    __shared__ float cs[64], rs[64];

    rl[lane] = bf2f(q_ws[b * 64 + lane]);

    float ctxp = 0.f;
    u32 cur[16], nxt[16];
    {
        const u32* pk0 = PK + ((size_t)(b * NSEG + 0) << 12);
#pragma unroll
        for (int jj = 0; jj < 16; ++jj)
            cur[jj] = pk0[(p * 16 + jj) * 64 + lane];
    }
    __syncthreads();

    for (int s = 0; s < NSEG; ++s) {
        const int sn = (s + 1 < NSEG) ? s + 1 : s;
        const u32* pkn = PK + ((size_t)(b * NSEG + sn) << 12);
#pragma unroll
        for (int jj = 0; jj < 16; ++jj)
            nxt[jj] = pkn[(p * 16 + jj) * 64 + lane];

        float accr = 0.f;
#pragma unroll
        for (int jj = 0; jj < 16; ++jj) {
            const u32 pv = cur[jj];
            const float Sv = __uint_as_float(pv & 0xFFFF0000u);
            const float Vv = __uint_as_float(pv << 16);
            const float rj = rl[p * 16 + jj];
            accr = fmaf(Sv, rj, accr);
            ctxp = fmaf(Vv, rj, ctxp);
        }
        psum[p][lane] = accr;
        __syncthreads();
        const float rn = (psum[0][lane] + psum[1][lane]) + (psum[2][lane] + psum[3][lane]);
        __syncthreads();
        rl[lane] = rn;

#pragma unroll
        for (int jj = 0; jj < 16; ++jj) cur[jj] = nxt[jj];
    }

    psum[p][lane] = ctxp;
    __syncthreads();
    if (t < 64)
        cs[t] = (psum[0][t] + psum[1][t]) + (psum[2][t] + psum[3][t]);
    __syncthreads();

    float rv = (p == 0) ? br[lane] : 0.f;
#pragma unroll
    for (int i = 0; i < 16; ++i)
        rv = fmaf(cs[p * 16 + i], Wr[(p * 16 + i) * HDIM + lane], rv);
    psum[p][lane] = rv;
    __syncthreads();
    if (t < 64)
        rs[t] = (psum[0][t] + psum[1][t]) + (psum[2][t] + psum[3][t]);
    __syncthreads();

    float ov = (p == 0) ? bo[lane] : 0.f;
#pragma unroll
    for (int i = 0; i < 16; ++i)
        ov = fmaf(rs[p * 16 + i], Wo[(p * 16 + i) * HDIM + lane], ov);
    psum[p][lane] = ov;
    __syncthreads();
    if (t < 64)
        out[(size_t)b * HDIM + t] = (psum[0][t] + psum[1][t]) + (psum[2][t] + psum[3][t]);
}

// ---------------------------------------------------------------------------
extern "C" void kernel_launch(void* const* d_in, const int* in_sizes, int n_in,
                              void* d_out, int out_size, void* d_ws, size_t ws_size,
                              hipStream_t stream)
{
    const int*   seq   = (const int*)  d_in[0];
    const float* embed = (const float*)d_in[1];
    const float* W1    = (const float*)d_in[2];
    const float* b1    = (const float*)d_in[3];
    const float* W2    = (const float*)d_in[4];
    const float* b2    = (const float*)d_in[5];
    const float* gamma = (const float*)d_in[6];
    const float* beta  = (const float*)d_in[7];
    const float* Wr    = (const float*)d_in[8];
    const float* br    = (const float*)d_in[9];
    const float* Wo    = (const float*)d_in[10];
    const float* bo    = (const float*)d_in[11];

    u32* pk_ws = (u32*)d_ws;                                  // 8 MB (16*32*4096 u32)
    u16* q_ws  = (u16*)(pk_ws + (size_t)BATCH * NSEG * 4096); // 2 KB
    float* outp = (float*)d_out;

    hipLaunchKernelGGL(fused_pc_kernel, dim3(BATCH * NSEG), dim3(256), 0, stream,
                       seq, embed, W1, b1, W2, b2, gamma, beta, pk_ws, q_ws);
    hipLaunchKernelGGL(final_kernel, dim3(BATCH), dim3(256), 0, stream,
                       q_ws, pk_ws, Wr, br, Wo, bo, outp);
}